// Round 3
// baseline (596.211 us; speedup 1.0000x reference)
//
#include <hip/hip_runtime.h>
#include <math.h>

#define B 4
#define T 1024
#define C 768
#define NH 12
#define HS 64
#define ESCALE 10.0f
#define KBUP 5.0f

__device__ inline unsigned short f2b(float f) {
  union { float f; unsigned int u; } x;
  x.f = f;
  unsigned int r = (x.u + 0x7FFF + ((x.u >> 16) & 1)) >> 16;
  return (unsigned short)r;
}
__device__ inline float b2f(unsigned short u) {
  union { float f; unsigned int i; } x;
  x.i = ((unsigned int)u) << 16;
  return x.f;
}

// ---------------- GEMM: out = X @ W^T ----------------
// X [M,K] fp32, W [N,K] fp32.
// OUTK=0: fp32 token-major [M,N].  OUTK=1: bf16 head-major [B,NH,T,HS].
template <int OUTK>
__global__ __launch_bounds__(256) void gemm_wt(const float* __restrict__ X,
                                               const float* __restrict__ W,
                                               void* __restrict__ outp,
                                               int M, int K) {
  __shared__ __attribute__((aligned(16))) float xs[64][20];
  __shared__ __attribute__((aligned(16))) float wst[16][68];
  const int tid = threadIdx.x;
  const int m0 = blockIdx.x * 64;
  const int n0 = blockIdx.y * 64;
  const int ty = tid >> 4, tx = tid & 15;
  const int lr = tid >> 2, lq = (tid & 3) << 2;
  float acc[4][4] = {};
  for (int k0 = 0; k0 < K; k0 += 16) {
    float4 xa = *(const float4*)(X + (size_t)(m0 + lr) * K + k0 + lq);
    float4 wa = *(const float4*)(W + (size_t)(n0 + lr) * K + k0 + lq);
    *(float4*)&xs[lr][lq] = xa;
    wst[lq + 0][lr] = wa.x;
    wst[lq + 1][lr] = wa.y;
    wst[lq + 2][lr] = wa.z;
    wst[lq + 3][lr] = wa.w;
    __syncthreads();
#pragma unroll
    for (int k4 = 0; k4 < 4; ++k4) {
      float a4[4][4] __attribute__((aligned(16)));
#pragma unroll
      for (int i = 0; i < 4; ++i)
        *(float4*)a4[i] = *(const float4*)&xs[ty * 4 + i][k4 * 4];
#pragma unroll
      for (int kk = 0; kk < 4; ++kk) {
        float b4[4] __attribute__((aligned(16)));
        *(float4*)b4 = *(const float4*)&wst[k4 * 4 + kk][tx * 4];
#pragma unroll
        for (int i = 0; i < 4; ++i)
#pragma unroll
          for (int j = 0; j < 4; ++j) acc[i][j] += a4[i][kk] * b4[j];
      }
    }
    __syncthreads();
  }
  if (OUTK == 1) {
    unsigned short* out = (unsigned short*)outp;
    const int h = n0 >> 6;
    const int d0 = tx * 4;
#pragma unroll
    for (int i = 0; i < 4; ++i) {
      int m = m0 + ty * 4 + i;
      int bb = m / T, t = m % T;
      ushort4 r;
      r.x = f2b(acc[i][0]);
      r.y = f2b(acc[i][1]);
      r.z = f2b(acc[i][2]);
      r.w = f2b(acc[i][3]);
      *(ushort4*)(out + (((size_t)(bb * NH + h) * T + t) * HS) + d0) = r;
    }
  } else {
    float* out = (float*)outp;
#pragma unroll
    for (int i = 0; i < 4; ++i) {
      int m = m0 + ty * 4 + i;
      float4 r = make_float4(acc[i][0], acc[i][1], acc[i][2], acc[i][3]);
      *(float4*)(out + (size_t)m * C + n0 + tx * 4) = r;
    }
  }
}

// ---------------- v mixing + normalize (fp32 in -> bf16 head-major out) ----
__global__ __launch_bounds__(256) void vcompute(const float* __restrict__ lin,
                                                const float* __restrict__ coef,
                                                const float* __restrict__ vbeta,
                                                unsigned short* __restrict__ vout) {
  int w = (blockIdx.x * 256 + threadIdx.x) >> 6;
  int lane = threadIdx.x & 63;
  int t = w % T;
  int h = (w / T) % NH;
  int b = w / (T * NH);
  float c = coef[h];
  float vh = lin[((size_t)(b * T + t)) * C + h * HS + lane];
  float vs = (t + 1 < T) ? lin[((size_t)(b * T + t + 1)) * C + h * HS + lane] : 0.0f;
  float v = vs * (1.0f - c) + vh * c;
  float ss = v * v;
#pragma unroll
  for (int off = 1; off < 64; off <<= 1) ss += __shfl_xor(ss, off);
  float scale = rsqrtf(ss) * expf(vbeta[h] * ESCALE);
  vout[(((size_t)(b * NH + h) * T + t) * HS) + lane] = f2b(v * scale);
}

// ---------------- EMA over time (in place bf16, fp32 register state) -------
__global__ void ema_kernel(unsigned short* __restrict__ kb, const float* __restrict__ lkb) {
  int tid = blockIdx.x * blockDim.x + threadIdx.x;
  if (tid >= B * NH * HS) return;
  int d = tid & (HS - 1);
  int h = (tid / HS) % NH;
  int b = tid / (HS * NH);
  float lam = fabsf(lkb[h]) * ESCALE;
  float a = expf(-lam), w = 1.0f - a;
  unsigned short* p = kb + ((size_t)(b * NH + h) * T) * HS + d;
  float s = 0.0f;
  for (int t = 0; t < T; ++t) {
    s = a * s + w * b2f(p[(size_t)t * HS]);
    p[(size_t)t * HS] = f2b(s);
  }
}

// ---------------- k normalize + kb scale (in place bf16) -------------------
__global__ __launch_bounds__(256) void knorm(unsigned short* __restrict__ kb,
                                             const float* __restrict__ kbeta) {
  int w = (blockIdx.x * 256 + threadIdx.x) >> 6;
  int lane = threadIdx.x & 63;
  int t = w % T;
  int h = (w / T) % NH;
  int b = w / (T * NH);
  size_t idx = (((size_t)(b * NH + h) * T + t) * HS) + lane;
  float v = b2f(kb[idx]);
  float ss = v * v;
#pragma unroll
  for (int off = 1; off < 64; off <<= 1) ss += __shfl_xor(ss, off);
  float scale = rsqrtf(ss) * expf(fminf(kbeta[h] * ESCALE, KBUP));
  kb[idx] = f2b(v * scale);
}

// ---------------- flash-style causal (shift-1) attention -------------------
// K,V bf16 head-major; Y fp32 token-major.
__global__ __launch_bounds__(256) void attn_kernel(const unsigned short* __restrict__ Km,
                                                   const unsigned short* __restrict__ Vm,
                                                   float* __restrict__ Y) {
  const int bh = blockIdx.y;
  const int b = bh / NH, h = bh % NH;
  const int qi0 = blockIdx.x * 64;
  __shared__ __attribute__((aligned(16))) float qs[64][68];
  __shared__ __attribute__((aligned(16))) float kps[64][68];  // kst in S-phase, ps in PV-phase
  __shared__ __attribute__((aligned(16))) float vsh[64][68];
  const unsigned short* Kb = Km + (size_t)bh * T * HS;
  const unsigned short* Vb = Vm + (size_t)bh * T * HS;
  const int tid = threadIdx.x;
  const int ty = tid >> 4, tx = tid & 15;
  const int srow = tid >> 4;
  const int scol = (tid & 15) * 4;
  // stage Q (rows of k for this q-tile)
#pragma unroll
  for (int rr = 0; rr < 4; ++rr) {
    int r = rr * 16 + srow;
    ushort4 qu = *(const ushort4*)(Kb + (size_t)(qi0 + r) * HS + scol);
    *(float4*)&qs[r][scol] = make_float4(b2f(qu.x), b2f(qu.y), b2f(qu.z), b2f(qu.w));
  }
  float m_st[4], l_st[4], acc[4][4];
#pragma unroll
  for (int i = 0; i < 4; ++i) {
    m_st[i] = -INFINITY;
    l_st[i] = 0.0f;
#pragma unroll
    for (int j = 0; j < 4; ++j) acc[i][j] = 0.0f;
  }
  const int njt = blockIdx.x + 1;
  for (int jt = 0; jt < njt; ++jt) {
    const int j0 = jt * 64;
    __syncthreads();  // protect kps/vsh from previous-iter reads (covers Q stage on iter 0)
#pragma unroll
    for (int rr = 0; rr < 4; ++rr) {
      int r = rr * 16 + srow;
      ushort4 ku = *(const ushort4*)(Kb + (size_t)(j0 + r) * HS + scol);
      kps[scol + 0][r] = b2f(ku.x);
      kps[scol + 1][r] = b2f(ku.y);
      kps[scol + 2][r] = b2f(ku.z);
      kps[scol + 3][r] = b2f(ku.w);
      ushort4 vu = *(const ushort4*)(Vb + (size_t)(j0 + r) * HS + scol);
      *(float4*)&vsh[r][scol] = make_float4(b2f(vu.x), b2f(vu.y), b2f(vu.z), b2f(vu.w));
    }
    __syncthreads();
    // S = q . k^T  (kps holds k-tile transposed: kps[kk][j])
    float s[4][4];
#pragma unroll
    for (int i = 0; i < 4; ++i)
#pragma unroll
      for (int j = 0; j < 4; ++j) s[i][j] = 0.0f;
#pragma unroll
    for (int k4 = 0; k4 < 16; ++k4) {
      float a4[4][4] __attribute__((aligned(16)));
#pragma unroll
      for (int i = 0; i < 4; ++i)
        *(float4*)a4[i] = *(const float4*)&qs[ty * 4 + i][k4 * 4];
#pragma unroll
      for (int kk = 0; kk < 4; ++kk) {
        float b4[4] __attribute__((aligned(16)));
        *(float4*)b4 = *(const float4*)&kps[k4 * 4 + kk][tx * 4];
#pragma unroll
        for (int i = 0; i < 4; ++i)
#pragma unroll
          for (int j = 0; j < 4; ++j) s[i][j] += a4[i][kk] * b4[j];
      }
    }
    // mask: only the diagonal tile needs it (allowed = jj <= ii-1)
    if (jt == njt - 1) {
#pragma unroll
      for (int i = 0; i < 4; ++i) {
        int ii = qi0 + ty * 4 + i;
#pragma unroll
        for (int j = 0; j < 4; ++j) {
          int jj = j0 + tx * 4 + j;
          if (jj >= ii) s[i][j] = -INFINITY;
        }
      }
    }
    __syncthreads();  // all kst reads done; kps becomes ps
    // online softmax update
#pragma unroll
    for (int i = 0; i < 4; ++i) {
      float rm = fmaxf(fmaxf(s[i][0], s[i][1]), fmaxf(s[i][2], s[i][3]));
#pragma unroll
      for (int off = 1; off < 16; off <<= 1) rm = fmaxf(rm, __shfl_xor(rm, off));
      float mnew = fmaxf(m_st[i], rm);
      float scale = (mnew == -INFINITY) ? 1.0f : expf(m_st[i] - mnew);
      float p[4], rs = 0.0f;
#pragma unroll
      for (int j = 0; j < 4; ++j) {
        p[j] = (s[i][j] == -INFINITY) ? 0.0f : expf(s[i][j] - mnew);
        rs += p[j];
      }
#pragma unroll
      for (int off = 1; off < 16; off <<= 1) rs += __shfl_xor(rs, off);
      l_st[i] = l_st[i] * scale + rs;
      m_st[i] = mnew;
#pragma unroll
      for (int j = 0; j < 4; ++j) acc[i][j] *= scale;
      *(float4*)&kps[ty * 4 + i][tx * 4] = make_float4(p[0], p[1], p[2], p[3]);
    }
    __syncthreads();
    // acc += P @ V
#pragma unroll
    for (int k4 = 0; k4 < 16; ++k4) {
      float a4[4][4] __attribute__((aligned(16)));
#pragma unroll
      for (int i = 0; i < 4; ++i)
        *(float4*)a4[i] = *(const float4*)&kps[ty * 4 + i][k4 * 4];
#pragma unroll
      for (int kk = 0; kk < 4; ++kk) {
        float b4[4] __attribute__((aligned(16)));
        *(float4*)b4 = *(const float4*)&vsh[k4 * 4 + kk][tx * 4];
#pragma unroll
        for (int i = 0; i < 4; ++i)
#pragma unroll
          for (int j = 0; j < 4; ++j) acc[i][j] += a4[i][kk] * b4[j];
      }
    }
  }
  // epilogue: y = acc / l (0 for fully-masked row 0)
#pragma unroll
  for (int i = 0; i < 4; ++i) {
    int r = qi0 + ty * 4 + i;
    float inv = (l_st[i] > 0.0f) ? 1.0f / l_st[i] : 0.0f;
    float4 o = make_float4(acc[i][0] * inv, acc[i][1] * inv, acc[i][2] * inv, acc[i][3] * inv);
    *(float4*)(Y + ((size_t)(b * T + r)) * C + h * HS + tx * 4) = o;
  }
}

extern "C" void kernel_launch(void* const* d_in, const int* in_sizes, int n_in,
                              void* d_out, int out_size, void* d_ws, size_t ws_size,
                              hipStream_t stream) {
  const float* x = (const float*)d_in[0];
  const float* conv_w = (const float*)d_in[1];
  const float* lin_w = (const float*)d_in[2];
  const float* coef = (const float*)d_in[3];
  const float* lkb = (const float*)d_in[4];
  const float* kbeta = (const float*)d_in[5];
  const float* vbeta = (const float*)d_in[6];
  const float* proj_w = (const float*)d_in[7];

  // Workspace budget: exactly NE*4 bytes = 12.58 MB (== d_out size).
  //   phase 1: kbuf bf16 [NE] | vbuf bf16 [NE]      (ws)
  //            lin fp32 -> y fp32                   (d_out, lin dead before y)
  //   phase 2: proj result fp32 [NE]                (ws, k/v dead)
  //   final  : D2D copy ws -> d_out
  const size_t NE = (size_t)B * T * C;
  unsigned short* kbuf = (unsigned short*)d_ws;  // bf16 [B,NH,T,HS]
  unsigned short* vbuf = kbuf + NE;              // bf16 [B,NH,T,HS]
  float* linbuf = (float*)d_out;                 // fp32 [B,T,C]
  float* ybuf = (float*)d_out;                   // fp32 [B,T,C] (overwrites lin)
  float* outtmp = (float*)d_ws;                  // fp32 [B,T,C] (overlays k+v)

  dim3 ggrid(64, 12);
  gemm_wt<1><<<ggrid, 256, 0, stream>>>(x, conv_w, kbuf, B * T, C);
  gemm_wt<0><<<ggrid, 256, 0, stream>>>(x, lin_w, linbuf, B * T, C);
  vcompute<<<(B * NH * T) / 4, 256, 0, stream>>>(linbuf, coef, vbeta, vbuf);
  ema_kernel<<<12, 256, 0, stream>>>(kbuf, lkb);
  knorm<<<(B * NH * T) / 4, 256, 0, stream>>>(kbuf, kbeta);
  attn_kernel<<<dim3(T / 64, B * NH), 256, 0, stream>>>(kbuf, vbuf, ybuf);
  gemm_wt<0><<<ggrid, 256, 0, stream>>>(ybuf, proj_w, outtmp, B * T, C);
  hipMemcpyAsync(d_out, outtmp, NE * sizeof(float), hipMemcpyDeviceToDevice, stream);
}

// Round 5
// 397.653 us; speedup vs baseline: 1.4993x; 1.4993x over previous
//
#include <hip/hip_runtime.h>
#include <math.h>

#define B 4
#define T 1024
#define C 768
#define NH 12
#define HS 64
#define ESCALE 10.0f
#define KBUP 5.0f

typedef short bf16x8 __attribute__((ext_vector_type(8)));
typedef short bf16x4v __attribute__((ext_vector_type(4)));
typedef float f32x4 __attribute__((ext_vector_type(4)));

__device__ inline unsigned short f2b(float f) {
  union { float f; unsigned int u; } x;
  x.f = f;
  unsigned int r = (x.u + 0x7FFF + ((x.u >> 16) & 1)) >> 16;
  return (unsigned short)r;
}
__device__ inline float b2f(unsigned short u) {
  union { float f; unsigned int i; } x;
  x.i = ((unsigned int)u) << 16;
  return x.f;
}

// ---------------- GEMM: out = X @ W^T ----------------
// X [M,K] fp32, W [N,K] fp32.
// OUTK=0: fp32 token-major [M,N].  OUTK=1: bf16 head-major [B,NH,T,HS].
template <int OUTK>
__global__ __launch_bounds__(256) void gemm_wt(const float* __restrict__ X,
                                               const float* __restrict__ W,
                                               void* __restrict__ outp,
                                               int M, int K) {
  __shared__ __attribute__((aligned(16))) float xs[64][20];
  __shared__ __attribute__((aligned(16))) float wst[16][68];
  const int tid = threadIdx.x;
  const int m0 = blockIdx.x * 64;
  const int n0 = blockIdx.y * 64;
  const int ty = tid >> 4, tx = tid & 15;
  const int lr = tid >> 2, lq = (tid & 3) << 2;
  float acc[4][4] = {};
  for (int k0 = 0; k0 < K; k0 += 16) {
    float4 xa = *(const float4*)(X + (size_t)(m0 + lr) * K + k0 + lq);
    float4 wa = *(const float4*)(W + (size_t)(n0 + lr) * K + k0 + lq);
    *(float4*)&xs[lr][lq] = xa;
    wst[lq + 0][lr] = wa.x;
    wst[lq + 1][lr] = wa.y;
    wst[lq + 2][lr] = wa.z;
    wst[lq + 3][lr] = wa.w;
    __syncthreads();
#pragma unroll
    for (int k4 = 0; k4 < 4; ++k4) {
      float a4[4][4] __attribute__((aligned(16)));
#pragma unroll
      for (int i = 0; i < 4; ++i)
        *(float4*)a4[i] = *(const float4*)&xs[ty * 4 + i][k4 * 4];
#pragma unroll
      for (int kk = 0; kk < 4; ++kk) {
        float b4[4] __attribute__((aligned(16)));
        *(float4*)b4 = *(const float4*)&wst[k4 * 4 + kk][tx * 4];
#pragma unroll
        for (int i = 0; i < 4; ++i)
#pragma unroll
          for (int j = 0; j < 4; ++j) acc[i][j] += a4[i][kk] * b4[j];
      }
    }
    __syncthreads();
  }
  if (OUTK == 1) {
    unsigned short* out = (unsigned short*)outp;
    const int h = n0 >> 6;
    const int d0 = tx * 4;
#pragma unroll
    for (int i = 0; i < 4; ++i) {
      int m = m0 + ty * 4 + i;
      int bb = m / T, t = m % T;
      ushort4 r;
      r.x = f2b(acc[i][0]);
      r.y = f2b(acc[i][1]);
      r.z = f2b(acc[i][2]);
      r.w = f2b(acc[i][3]);
      *(ushort4*)(out + (((size_t)(bb * NH + h) * T + t) * HS) + d0) = r;
    }
  } else {
    float* out = (float*)outp;
#pragma unroll
    for (int i = 0; i < 4; ++i) {
      int m = m0 + ty * 4 + i;
      float4 r = make_float4(acc[i][0], acc[i][1], acc[i][2], acc[i][3]);
      *(float4*)(out + (size_t)m * C + n0 + tx * 4) = r;
    }
  }
}

// ---------------- v mixing + normalize (fp32 in -> bf16 head-major out) ----
__global__ __launch_bounds__(256) void vcompute(const float* __restrict__ lin,
                                                const float* __restrict__ coef,
                                                const float* __restrict__ vbeta,
                                                unsigned short* __restrict__ vout) {
  int w = (blockIdx.x * 256 + threadIdx.x) >> 6;
  int lane = threadIdx.x & 63;
  int t = w % T;
  int h = (w / T) % NH;
  int b = w / (T * NH);
  float c = coef[h];
  float vh = lin[((size_t)(b * T + t)) * C + h * HS + lane];
  float vs = (t + 1 < T) ? lin[((size_t)(b * T + t + 1)) * C + h * HS + lane] : 0.0f;
  float v = vs * (1.0f - c) + vh * c;
  float ss = v * v;
#pragma unroll
  for (int off = 1; off < 64; off <<= 1) ss += __shfl_xor(ss, off);
  float scale = rsqrtf(ss) * expf(vbeta[h] * ESCALE);
  vout[(((size_t)(b * NH + h) * T + t) * HS) + lane] = f2b(v * scale);
}

// ---------------- EMA over time (in place bf16, fp32 register state) -------
__global__ void ema_kernel(unsigned short* __restrict__ kb, const float* __restrict__ lkb) {
  int tid = blockIdx.x * blockDim.x + threadIdx.x;
  if (tid >= B * NH * HS) return;
  int d = tid & (HS - 1);
  int h = (tid / HS) % NH;
  int b = tid / (HS * NH);
  float lam = fabsf(lkb[h]) * ESCALE;
  float a = expf(-lam), w = 1.0f - a;
  unsigned short* p = kb + ((size_t)(b * NH + h) * T) * HS + d;
  float s = 0.0f;
  for (int t = 0; t < T; ++t) {
    s = a * s + w * b2f(p[(size_t)t * HS]);
    p[(size_t)t * HS] = f2b(s);
  }
}

// ---------------- k normalize + kb scale (in place bf16) -------------------
__global__ __launch_bounds__(256) void knorm(unsigned short* __restrict__ kb,
                                             const float* __restrict__ kbeta) {
  int w = (blockIdx.x * 256 + threadIdx.x) >> 6;
  int lane = threadIdx.x & 63;
  int t = w % T;
  int h = (w / T) % NH;
  int b = w / (T * NH);
  size_t idx = (((size_t)(b * NH + h) * T + t) * HS) + lane;
  float v = b2f(kb[idx]);
  float ss = v * v;
#pragma unroll
  for (int off = 1; off < 64; off <<= 1) ss += __shfl_xor(ss, off);
  float scale = rsqrtf(ss) * expf(fminf(kbeta[h] * ESCALE, KBUP));
  kb[idx] = f2b(v * scale);
}

// ---------------- MFMA flash attention (bf16 K/V, swapped-QK^T) ------------
// Per block: 64 q-rows, 4 waves x 16 rows. K/V tiles 64x64 staged in LDS
// (padded row stride 72 -> conflict-free). S^T = mfma(K, Q) so P rows pack
// into 8-B LDS writes; PV computes O^T = mfma(V^T, P^T).
__global__ __launch_bounds__(256) void attn_mfma(const unsigned short* __restrict__ Km,
                                                 const unsigned short* __restrict__ Vm,
                                                 float* __restrict__ Y) {
  const int bid = blockIdx.x;
  const int qt = 15 - (bid / (B * NH));  // heavy q-tiles first
  const int bh = bid % (B * NH);
  const int b = bh / NH, h = bh % NH;
  const int qi0 = qt * 64;
  const short* Kb = (const short*)(Km + (size_t)bh * T * HS);
  const short* Vb = (const short*)(Vm + (size_t)bh * T * HS);
  __shared__ short kt[64 * 72];       // K-tile row-major [j][d]
  __shared__ short vt[64 * 72];       // V-tile transposed [d][j]
  __shared__ short pl[4 * 16 * 72];   // per-wave P [i][j]
  const int tid = threadIdx.x;
  const int w = tid >> 6, lane = tid & 63;
  const int qr = lane & 15, qg = lane >> 4;

  // Q fragments in registers (B-operand: col=lane&15, k-chunk=(lane>>4)*8)
  bf16x8 qf0 = *(const bf16x8*)(Kb + (size_t)(qi0 + w * 16 + qr) * HS + qg * 8);
  bf16x8 qf1 = *(const bf16x8*)(Kb + (size_t)(qi0 + w * 16 + qr) * HS + qg * 8 + 32);

  f32x4 o[4];
#pragma unroll
  for (int db = 0; db < 4; ++db) o[db] = (f32x4){0.f, 0.f, 0.f, 0.f};
  float m_st = -INFINITY, l_st = 0.0f;

  const int njt = qt + 1;
  for (int jt = 0; jt < njt; ++jt) {
    const int j0 = jt * 64;
    __syncthreads();
    // ---- stage K row-major and V transposed ----
#pragma unroll
    for (int it = 0; it < 2; ++it) {
      int idx = tid + it * 256;
      int row = idx >> 3, ch = idx & 7;
      *(bf16x8*)&kt[row * 72 + ch * 8] =
          *(const bf16x8*)(Kb + (size_t)(j0 + row) * HS + ch * 8);
      int vj = idx & 63, vd0 = (idx >> 6) * 8;
      bf16x8 vv = *(const bf16x8*)(Vb + (size_t)(j0 + vj) * HS + vd0);
#pragma unroll
      for (int e = 0; e < 8; ++e) vt[(vd0 + e) * 72 + vj] = vv[e];
    }
    __syncthreads();
    // ---- S^T = K . Q^T : D[j][i], col i = lane&15, rows j = qg*4+r+16*jb ----
    f32x4 st[4];
#pragma unroll
    for (int jb = 0; jb < 4; ++jb) st[jb] = (f32x4){0.f, 0.f, 0.f, 0.f};
#pragma unroll
    for (int jb = 0; jb < 4; ++jb) {
      bf16x8 kf0 = *(const bf16x8*)&kt[(qr + 16 * jb) * 72 + qg * 8];
      bf16x8 kf1 = *(const bf16x8*)&kt[(qr + 16 * jb) * 72 + qg * 8 + 32];
      st[jb] = __builtin_amdgcn_mfma_f32_16x16x32_bf16(kf0, qf0, st[jb], 0, 0, 0);
      st[jb] = __builtin_amdgcn_mfma_f32_16x16x32_bf16(kf1, qf1, st[jb], 0, 0, 0);
    }
    // ---- mask (diagonal tile only): allowed = jj <= ii-1 ----
    if (jt == njt - 1) {
      const int ii = qi0 + w * 16 + qr;
#pragma unroll
      for (int jb = 0; jb < 4; ++jb)
#pragma unroll
        for (int r = 0; r < 4; ++r) {
          int jj = j0 + 16 * jb + qg * 4 + r;
          if (jj >= ii) st[jb][r] = -INFINITY;
        }
    }
    // ---- online softmax (per q-row i = lane&15; j spread over qg,reg,jb) ----
    float rm = -INFINITY;
#pragma unroll
    for (int jb = 0; jb < 4; ++jb)
#pragma unroll
      for (int r = 0; r < 4; ++r) rm = fmaxf(rm, st[jb][r]);
    rm = fmaxf(rm, __shfl_xor(rm, 16));
    rm = fmaxf(rm, __shfl_xor(rm, 32));
    float mnew = fmaxf(m_st, rm);
    float scale = (mnew == -INFINITY) ? 1.0f : __expf(m_st - mnew);
    float p[4][4];
    float rs = 0.0f;
#pragma unroll
    for (int jb = 0; jb < 4; ++jb)
#pragma unroll
      for (int r = 0; r < 4; ++r) {
        float pv = (st[jb][r] == -INFINITY) ? 0.0f : __expf(st[jb][r] - mnew);
        p[jb][r] = pv;
        rs += pv;
      }
    rs += __shfl_xor(rs, 16);
    rs += __shfl_xor(rs, 32);
    l_st = l_st * scale + rs;
    m_st = mnew;
#pragma unroll
    for (int db = 0; db < 4; ++db) o[db] *= scale;
    // ---- P -> LDS (packed 8B writes, row-major [i][j]) ----
#pragma unroll
    for (int jb = 0; jb < 4; ++jb) {
      bf16x4v pw;
#pragma unroll
      for (int r = 0; r < 4; ++r) pw[r] = (short)f2b(p[jb][r]);
      *(bf16x4v*)&pl[w * 1152 + qr * 72 + jb * 16 + qg * 4] = pw;
    }
    // ---- O^T += V^T . P^T ----
#pragma unroll
    for (int ks = 0; ks < 2; ++ks) {
      bf16x8 pf = *(const bf16x8*)&pl[w * 1152 + qr * 72 + ks * 32 + qg * 8];
#pragma unroll
      for (int db = 0; db < 4; ++db) {
        bf16x8 vf = *(const bf16x8*)&vt[(qr + 16 * db) * 72 + qg * 8 + ks * 32];
        o[db] = __builtin_amdgcn_mfma_f32_16x16x32_bf16(vf, pf, o[db], 0, 0, 0);
      }
    }
  }
  // ---- epilogue: y = o / l (0 for fully-masked row 0) ----
  float inv = (l_st > 0.0f) ? 1.0f / l_st : 0.0f;
#pragma unroll
  for (int db = 0; db < 4; ++db) {
    f32x4 ov = o[db] * inv;
    *(f32x4*)(Y + (size_t)(b * T + qi0 + w * 16 + qr) * C + h * HS + db * 16 + qg * 4) = ov;
  }
}

extern "C" void kernel_launch(void* const* d_in, const int* in_sizes, int n_in,
                              void* d_out, int out_size, void* d_ws, size_t ws_size,
                              hipStream_t stream) {
  const float* x = (const float*)d_in[0];
  const float* conv_w = (const float*)d_in[1];
  const float* lin_w = (const float*)d_in[2];
  const float* coef = (const float*)d_in[3];
  const float* lkb = (const float*)d_in[4];
  const float* kbeta = (const float*)d_in[5];
  const float* vbeta = (const float*)d_in[6];
  const float* proj_w = (const float*)d_in[7];

  // Workspace budget: exactly NE*4 bytes = 12.58 MB (== d_out size).
  const size_t NE = (size_t)B * T * C;
  unsigned short* kbuf = (unsigned short*)d_ws;  // bf16 [B,NH,T,HS]
  unsigned short* vbuf = kbuf + NE;              // bf16 [B,NH,T,HS]
  float* linbuf = (float*)d_out;                 // fp32 [B,T,C]
  float* ybuf = (float*)d_out;                   // fp32 [B,T,C] (overwrites lin)
  float* outtmp = (float*)d_ws;                  // fp32 [B,T,C] (overlays k+v)

  dim3 ggrid(64, 12);
  gemm_wt<1><<<ggrid, 256, 0, stream>>>(x, conv_w, kbuf, B * T, C);
  gemm_wt<0><<<ggrid, 256, 0, stream>>>(x, lin_w, linbuf, B * T, C);
  vcompute<<<(B * NH * T) / 4, 256, 0, stream>>>(linbuf, coef, vbeta, vbuf);
  ema_kernel<<<12, 256, 0, stream>>>(kbuf, lkb);
  knorm<<<(B * NH * T) / 4, 256, 0, stream>>>(kbuf, kbeta);
  attn_mfma<<<T / 64 * B * NH, 256, 0, stream>>>(kbuf, vbuf, ybuf);
  gemm_wt<0><<<ggrid, 256, 0, stream>>>(ybuf, proj_w, outtmp, B * T, C);
  hipMemcpyAsync(d_out, outtmp, NE * sizeof(float), hipMemcpyDeviceToDevice, stream);
}

// Round 7
// 255.124 us; speedup vs baseline: 2.3369x; 1.5587x over previous
//
#include <hip/hip_runtime.h>
#include <math.h>

#define B 4
#define T 1024
#define C 768
#define NH 12
#define HS 64
#define ESCALE 10.0f
#define KBUP 5.0f

typedef short bf16x8 __attribute__((ext_vector_type(8)));
typedef short bf16x4v __attribute__((ext_vector_type(4)));
typedef float f32x4 __attribute__((ext_vector_type(4)));

__device__ inline unsigned short f2b(float f) {
  union { float f; unsigned int u; } x;
  x.f = f;
  unsigned int r = (x.u + 0x7FFF + ((x.u >> 16) & 1)) >> 16;
  return (unsigned short)r;
}
__device__ inline float b2f(unsigned short u) {
  union { float f; unsigned int i; } x;
  x.i = ((unsigned int)u) << 16;
  return x.f;
}

// ================= MFMA GEMM: out = X @ W^T (split-bf16) ==================
// MODE 0: X fp32 [4096][768]; W0=conv_w, W1=lin_w; N=1536.
//         n<768  -> out0 = k bf16 head-major [B,NH,T,HS]
//         n>=768 -> out1 = lin bf16 token-major [4096][768]
//         act split (hi+lo): acc += Ah*Bh + Ah*Bl + Al*Bh
// MODE 1: X bf16 [4096][768] (y); W0=proj_w; N=768; out0 fp32 token-major.
//         acc += A*Bh + A*Bl
template <int MODE>
__global__ __launch_bounds__(256) void gemm_mfma(const void* __restrict__ Xp,
                                                 const float* __restrict__ W0,
                                                 const float* __restrict__ W1,
                                                 void* __restrict__ out0,
                                                 void* __restrict__ out1) {
  const int K = 768;
  __shared__ short sa_hi[128][40];
  __shared__ short sa_lo[(MODE == 0) ? 128 : 1][40];
  __shared__ short sb_hi[128][40];
  __shared__ short sb_lo[128][40];
  const int tid = threadIdx.x;
  const int m0 = blockIdx.x * 128;
  const int n0 = blockIdx.y * 128;
  const int w = tid >> 6, lane = tid & 63;
  const int wm = w >> 1, wn = w & 1;
  const int r16 = lane & 15, g = lane >> 4;
  const float* Wsel = (MODE == 0 && n0 >= 768) ? (W1 + (size_t)(n0 - 768) * K)
                                               : (W0 + (size_t)n0 * K);
  f32x4 acc[4][4];
#pragma unroll
  for (int mi = 0; mi < 4; ++mi)
#pragma unroll
    for (int ni = 0; ni < 4; ++ni) acc[mi][ni] = (f32x4){0.f, 0.f, 0.f, 0.f};

  for (int k0 = 0; k0 < K; k0 += 32) {
    __syncthreads();
    // ---- stage W tile 128x32, split hi/lo ----
#pragma unroll
    for (int i = 0; i < 4; ++i) {
      int row = (tid >> 3) + 32 * i;
      int c = tid & 7;
      float4 wv = *(const float4*)(Wsel + (size_t)row * K + k0 + c * 4);
      bf16x4v hi, lo;
      float vv[4] = {wv.x, wv.y, wv.z, wv.w};
#pragma unroll
      for (int e = 0; e < 4; ++e) {
        unsigned short h = f2b(vv[e]);
        hi[e] = (short)h;
        lo[e] = (short)f2b(vv[e] - b2f(h));
      }
      *(bf16x4v*)&sb_hi[row][c * 4] = hi;
      *(bf16x4v*)&sb_lo[row][c * 4] = lo;
    }
    // ---- stage activation tile 128x32 ----
    if constexpr (MODE == 0) {
      const float* X = (const float*)Xp;
#pragma unroll
      for (int i = 0; i < 4; ++i) {
        int row = (tid >> 3) + 32 * i;
        int c = tid & 7;
        float4 xv = *(const float4*)(X + (size_t)(m0 + row) * K + k0 + c * 4);
        bf16x4v hi, lo;
        float vv[4] = {xv.x, xv.y, xv.z, xv.w};
#pragma unroll
        for (int e = 0; e < 4; ++e) {
          unsigned short h = f2b(vv[e]);
          hi[e] = (short)h;
          lo[e] = (short)f2b(vv[e] - b2f(h));
        }
        *(bf16x4v*)&sa_hi[row][c * 4] = hi;
        *(bf16x4v*)&sa_lo[row][c * 4] = lo;
      }
    } else {
      const unsigned short* X = (const unsigned short*)Xp;
#pragma unroll
      for (int i = 0; i < 2; ++i) {
        int row = (tid >> 2) + 64 * i;
        int c = tid & 3;
        *(bf16x8*)&sa_hi[row][c * 8] =
            *(const bf16x8*)(X + (size_t)(m0 + row) * K + k0 + c * 8);
      }
    }
    __syncthreads();
    // ---- fragments + MFMA ----
    bf16x8 ah[4], al[4], bh[4], bl[4];
#pragma unroll
    for (int mi = 0; mi < 4; ++mi) {
      ah[mi] = *(const bf16x8*)&sa_hi[wm * 64 + mi * 16 + r16][g * 8];
      if constexpr (MODE == 0)
        al[mi] = *(const bf16x8*)&sa_lo[wm * 64 + mi * 16 + r16][g * 8];
    }
#pragma unroll
    for (int ni = 0; ni < 4; ++ni) {
      bh[ni] = *(const bf16x8*)&sb_hi[wn * 64 + ni * 16 + r16][g * 8];
      bl[ni] = *(const bf16x8*)&sb_lo[wn * 64 + ni * 16 + r16][g * 8];
    }
#pragma unroll
    for (int mi = 0; mi < 4; ++mi)
#pragma unroll
      for (int ni = 0; ni < 4; ++ni) {
        acc[mi][ni] = __builtin_amdgcn_mfma_f32_16x16x32_bf16(ah[mi], bh[ni], acc[mi][ni], 0, 0, 0);
        acc[mi][ni] = __builtin_amdgcn_mfma_f32_16x16x32_bf16(ah[mi], bl[ni], acc[mi][ni], 0, 0, 0);
        if constexpr (MODE == 0)
          acc[mi][ni] = __builtin_amdgcn_mfma_f32_16x16x32_bf16(al[mi], bh[ni], acc[mi][ni], 0, 0, 0);
      }
  }
  // ---- epilogue: D[m-local = 4g+r][n-local = r16] per (mi,ni) ----
  if constexpr (MODE == 0) {
    if (n0 < 768) {
      unsigned short* ko = (unsigned short*)out0;
#pragma unroll
      for (int mi = 0; mi < 4; ++mi)
#pragma unroll
        for (int ni = 0; ni < 4; ++ni)
#pragma unroll
          for (int r = 0; r < 4; ++r) {
            int m = m0 + wm * 64 + mi * 16 + g * 4 + r;
            int n = n0 + wn * 64 + ni * 16 + r16;
            int bb = m >> 10, tt = m & 1023, h = n >> 6, d = n & 63;
            ko[(((size_t)(bb * NH + h)) * T + tt) * HS + d] = f2b(acc[mi][ni][r]);
          }
    } else {
      unsigned short* lo_ = (unsigned short*)out1;
#pragma unroll
      for (int mi = 0; mi < 4; ++mi)
#pragma unroll
        for (int ni = 0; ni < 4; ++ni)
#pragma unroll
          for (int r = 0; r < 4; ++r) {
            int m = m0 + wm * 64 + mi * 16 + g * 4 + r;
            int n = n0 + wn * 64 + ni * 16 + r16;
            lo_[(size_t)m * 768 + (n - 768)] = f2b(acc[mi][ni][r]);
          }
    }
  } else {
    float* oo = (float*)out0;
#pragma unroll
    for (int mi = 0; mi < 4; ++mi)
#pragma unroll
      for (int ni = 0; ni < 4; ++ni)
#pragma unroll
        for (int r = 0; r < 4; ++r) {
          int m = m0 + wm * 64 + mi * 16 + g * 4 + r;
          int n = n0 + wn * 64 + ni * 16 + r16;
          oo[(size_t)m * 768 + n] = acc[mi][ni][r];
        }
  }
}

// ---------------- v mixing + normalize (bf16 in -> bf16 head-major out) ----
__global__ __launch_bounds__(256) void vcompute(const unsigned short* __restrict__ lin,
                                                const float* __restrict__ coef,
                                                const float* __restrict__ vbeta,
                                                unsigned short* __restrict__ vout) {
  int w = (blockIdx.x * 256 + threadIdx.x) >> 6;
  int lane = threadIdx.x & 63;
  int t = w % T;
  int h = (w / T) % NH;
  int b = w / (T * NH);
  float c = coef[h];
  float vh = b2f(lin[((size_t)(b * T + t)) * C + h * HS + lane]);
  float vs = (t + 1 < T) ? b2f(lin[((size_t)(b * T + t + 1)) * C + h * HS + lane]) : 0.0f;
  float v = vs * (1.0f - c) + vh * c;
  float ss = v * v;
#pragma unroll
  for (int off = 1; off < 64; off <<= 1) ss += __shfl_xor(ss, off);
  float scale = rsqrtf(ss) * expf(vbeta[h] * ESCALE);
  vout[(((size_t)(b * NH + h) * T + t) * HS) + lane] = f2b(v * scale);
}

// -------- fused EMA (chunked scan, exact recurrence) + k-normalize ---------
// One block per (b,h): 4 waves x 256 time-steps, lanes = d. Pass 1 computes
// chunk-local end states; carry combine in LDS; pass 2 re-runs with correct
// init and writes normalized * kb k directly.
__global__ __launch_bounds__(256) void ema_norm(unsigned short* __restrict__ kb,
                                                const float* __restrict__ lkb,
                                                const float* __restrict__ kbeta) {
  const int bh = blockIdx.x;
  const int h = bh % NH;
  const int wv = threadIdx.x >> 6;   // time-chunk 0..3
  const int d = threadIdx.x & 63;
  const float lam = fabsf(lkb[h]) * ESCALE;
  const float a = expf(-lam), wf = 1.0f - a;
  const float a256 = expf(-lam * 256.0f);
  unsigned short* p = kb + ((size_t)bh * T) * HS + d;
  const int t0 = wv * 256;
  // pass 1: local scan from zero
  float s = 0.0f;
  for (int t = t0; t < t0 + 256; ++t) s = a * s + wf * b2f(p[(size_t)t * HS]);
  __shared__ float ends[4][64];
  ends[wv][d] = s;
  __syncthreads();
  float carry = 0.0f;
  for (int c = 0; c < wv; ++c) carry = a256 * carry + ends[c][d];
  // pass 2: exact state + fused normalize (wave lanes = full row)
  const float kbs = expf(fminf(kbeta[h] * ESCALE, KBUP));
  s = carry;
  for (int t = t0; t < t0 + 256; ++t) {
    s = a * s + wf * b2f(p[(size_t)t * HS]);
    float ss = s * s;
#pragma unroll
    for (int off = 1; off < 64; off <<= 1) ss += __shfl_xor(ss, off);
    p[(size_t)t * HS] = f2b(s * rsqrtf(ss) * kbs);
  }
}

// ---------------- MFMA flash attention (bf16 K/V, swapped-QK^T) ------------
__global__ __launch_bounds__(256) void attn_mfma(const unsigned short* __restrict__ Km,
                                                 const unsigned short* __restrict__ Vm,
                                                 unsigned short* __restrict__ Y) {
  const int bid = blockIdx.x;
  const int qt = 15 - (bid / (B * NH));  // heavy q-tiles first
  const int bh = bid % (B * NH);
  const int b = bh / NH, h = bh % NH;
  const int qi0 = qt * 64;
  const short* Kb = (const short*)(Km + (size_t)bh * T * HS);
  const short* Vb = (const short*)(Vm + (size_t)bh * T * HS);
  __shared__ short kt[64 * 72];       // K-tile row-major [j][d]
  __shared__ short vt[64 * 72];       // V-tile transposed [d][j]
  __shared__ short pl[4 * 16 * 72];   // per-wave P [i][j]
  const int tid = threadIdx.x;
  const int w = tid >> 6, lane = tid & 63;
  const int qr = lane & 15, qg = lane >> 4;

  bf16x8 qf0 = *(const bf16x8*)(Kb + (size_t)(qi0 + w * 16 + qr) * HS + qg * 8);
  bf16x8 qf1 = *(const bf16x8*)(Kb + (size_t)(qi0 + w * 16 + qr) * HS + qg * 8 + 32);

  f32x4 o[4];
#pragma unroll
  for (int db = 0; db < 4; ++db) o[db] = (f32x4){0.f, 0.f, 0.f, 0.f};
  float m_st = -INFINITY, l_st = 0.0f;

  const int njt = qt + 1;
  for (int jt = 0; jt < njt; ++jt) {
    const int j0 = jt * 64;
    __syncthreads();
#pragma unroll
    for (int it = 0; it < 2; ++it) {
      int idx = tid + it * 256;
      int row = idx >> 3, ch = idx & 7;
      *(bf16x8*)&kt[row * 72 + ch * 8] =
          *(const bf16x8*)(Kb + (size_t)(j0 + row) * HS + ch * 8);
      int vj = idx & 63, vd0 = (idx >> 6) * 8;
      bf16x8 vv = *(const bf16x8*)(Vb + (size_t)(j0 + vj) * HS + vd0);
#pragma unroll
      for (int e = 0; e < 8; ++e) vt[(vd0 + e) * 72 + vj] = vv[e];
    }
    __syncthreads();
    f32x4 st[4];
#pragma unroll
    for (int jb = 0; jb < 4; ++jb) st[jb] = (f32x4){0.f, 0.f, 0.f, 0.f};
#pragma unroll
    for (int jb = 0; jb < 4; ++jb) {
      bf16x8 kf0 = *(const bf16x8*)&kt[(qr + 16 * jb) * 72 + qg * 8];
      bf16x8 kf1 = *(const bf16x8*)&kt[(qr + 16 * jb) * 72 + qg * 8 + 32];
      st[jb] = __builtin_amdgcn_mfma_f32_16x16x32_bf16(kf0, qf0, st[jb], 0, 0, 0);
      st[jb] = __builtin_amdgcn_mfma_f32_16x16x32_bf16(kf1, qf1, st[jb], 0, 0, 0);
    }
    if (jt == njt - 1) {
      const int ii = qi0 + w * 16 + qr;
#pragma unroll
      for (int jb = 0; jb < 4; ++jb)
#pragma unroll
        for (int r = 0; r < 4; ++r) {
          int jj = j0 + 16 * jb + qg * 4 + r;
          if (jj >= ii) st[jb][r] = -INFINITY;
        }
    }
    float rm = -INFINITY;
#pragma unroll
    for (int jb = 0; jb < 4; ++jb)
#pragma unroll
      for (int r = 0; r < 4; ++r) rm = fmaxf(rm, st[jb][r]);
    rm = fmaxf(rm, __shfl_xor(rm, 16));
    rm = fmaxf(rm, __shfl_xor(rm, 32));
    float mnew = fmaxf(m_st, rm);
    float scale = (mnew == -INFINITY) ? 1.0f : __expf(m_st - mnew);
    float p[4][4];
    float rs = 0.0f;
#pragma unroll
    for (int jb = 0; jb < 4; ++jb)
#pragma unroll
      for (int r = 0; r < 4; ++r) {
        float pv = (st[jb][r] == -INFINITY) ? 0.0f : __expf(st[jb][r] - mnew);
        p[jb][r] = pv;
        rs += pv;
      }
    rs += __shfl_xor(rs, 16);
    rs += __shfl_xor(rs, 32);
    l_st = l_st * scale + rs;
    m_st = mnew;
#pragma unroll
    for (int db = 0; db < 4; ++db) o[db] *= scale;
#pragma unroll
    for (int jb = 0; jb < 4; ++jb) {
      bf16x4v pw;
#pragma unroll
      for (int r = 0; r < 4; ++r) pw[r] = (short)f2b(p[jb][r]);
      *(bf16x4v*)&pl[w * 1152 + qr * 72 + jb * 16 + qg * 4] = pw;
    }
#pragma unroll
    for (int ks = 0; ks < 2; ++ks) {
      bf16x8 pf = *(const bf16x8*)&pl[w * 1152 + qr * 72 + ks * 32 + qg * 8];
#pragma unroll
      for (int db = 0; db < 4; ++db) {
        bf16x8 vf = *(const bf16x8*)&vt[(qr + 16 * db) * 72 + qg * 8 + ks * 32];
        o[db] = __builtin_amdgcn_mfma_f32_16x16x32_bf16(vf, pf, o[db], 0, 0, 0);
      }
    }
  }
  float inv = (l_st > 0.0f) ? 1.0f / l_st : 0.0f;
#pragma unroll
  for (int db = 0; db < 4; ++db) {
    bf16x4v yv;
#pragma unroll
    for (int r = 0; r < 4; ++r) yv[r] = (short)f2b(o[db][r] * inv);
    *(bf16x4v*)(Y + (size_t)(b * T + qi0 + w * 16 + qr) * C + h * HS + db * 16 + qg * 4) = yv;
  }
}

extern "C" void kernel_launch(void* const* d_in, const int* in_sizes, int n_in,
                              void* d_out, int out_size, void* d_ws, size_t ws_size,
                              hipStream_t stream) {
  const float* x = (const float*)d_in[0];
  const float* conv_w = (const float*)d_in[1];
  const float* lin_w = (const float*)d_in[2];
  const float* coef = (const float*)d_in[3];
  const float* lkb = (const float*)d_in[4];
  const float* kbeta = (const float*)d_in[5];
  const float* vbeta = (const float*)d_in[6];
  const float* proj_w = (const float*)d_in[7];

  // ws = 2*NE bf16 = 12.58 MB (proven-safe footprint).
  //   A = ws[0:NE)  : lin bf16 (tok-major), later y bf16 (tok-major)
  //   B = ws[NE:2NE): k bf16 (head-major)
  // d_out: v bf16 [0:NE) during attention; final fp32 out overwrites all.
  const size_t NE = (size_t)B * T * C;
  unsigned short* abuf = (unsigned short*)d_ws;  // lin, then y
  unsigned short* kbuf = abuf + NE;              // k
  unsigned short* vbuf = (unsigned short*)d_out; // v (scratch phase)

  gemm_mfma<0><<<dim3(32, 12), 256, 0, stream>>>(x, conv_w, lin_w, kbuf, abuf);
  vcompute<<<(B * NH * T) / 4, 256, 0, stream>>>(abuf, coef, vbeta, vbuf);
  ema_norm<<<B * NH, 256, 0, stream>>>(kbuf, lkb, kbeta);
  attn_mfma<<<T / 64 * B * NH, 256, 0, stream>>>(kbuf, vbuf, abuf);
  gemm_mfma<1><<<dim3(32, 6), 256, 0, stream>>>(abuf, proj_w, nullptr, d_out, nullptr);
}

// Round 13
// 214.020 us; speedup vs baseline: 2.7858x; 1.1921x over previous
//
#include <hip/hip_runtime.h>
#include <math.h>

#define B 4
#define T 1024
#define C 768
#define NH 12
#define HS 64
#define ESCALE 10.0f
#define KBUP 5.0f
#define ECH 64
#define NCH (T / ECH)

typedef short bf16x8 __attribute__((ext_vector_type(8)));
typedef short bf16x4v __attribute__((ext_vector_type(4)));
typedef float f32x4 __attribute__((ext_vector_type(4)));

__device__ inline unsigned short f2b(float f) {
  union { float f; unsigned int u; } x;
  x.f = f;
  unsigned int r = (x.u + 0x7FFF + ((x.u >> 16) & 1)) >> 16;
  return (unsigned short)r;
}
__device__ inline float b2f(unsigned short u) {
  union { float f; unsigned int i; } x;
  x.i = ((unsigned int)u) << 16;
  return x.f;
}

// ================= MFMA GEMM: out = X @ W^T (split-bf16) ==================
// MODE 0: X fp32 [4096][768]; W0=conv_w, W1=lin_w; N=1536.
//         n<768  -> out0 = k bf16 head-major [B,NH,T,HS]
//         n>=768 -> out1 = lin bf16 token-major [4096][768]
//         act split (hi+lo): acc += Ah*Bh + Ah*Bl + Al*Bh
// MODE 1: X bf16 [4096][768] (y); W0=proj_w; N=768; out0 fp32 token-major.
//         acc += A*Bh + A*Bl
template <int MODE>
__global__ __launch_bounds__(256) void gemm_mfma(const void* __restrict__ Xp,
                                                 const float* __restrict__ W0,
                                                 const float* __restrict__ W1,
                                                 void* __restrict__ out0,
                                                 void* __restrict__ out1) {
  const int K = 768;
  __shared__ short sa_hi[128][40];
  __shared__ short sa_lo[(MODE == 0) ? 128 : 1][40];
  __shared__ short sb_hi[128][40];
  __shared__ short sb_lo[128][40];
  const int tid = threadIdx.x;
  const int m0 = blockIdx.x * 128;
  const int n0 = blockIdx.y * 128;
  const int w = tid >> 6, lane = tid & 63;
  const int wm = w >> 1, wn = w & 1;
  const int r16 = lane & 15, g = lane >> 4;
  const float* Wsel = (MODE == 0 && n0 >= 768) ? (W1 + (size_t)(n0 - 768) * K)
                                               : (W0 + (size_t)n0 * K);
  f32x4 acc[4][4];
#pragma unroll
  for (int mi = 0; mi < 4; ++mi)
#pragma unroll
    for (int ni = 0; ni < 4; ++ni) acc[mi][ni] = (f32x4){0.f, 0.f, 0.f, 0.f};

  for (int k0 = 0; k0 < K; k0 += 32) {
    __syncthreads();
    // ---- stage W tile 128x32, split hi/lo ----
#pragma unroll
    for (int i = 0; i < 4; ++i) {
      int row = (tid >> 3) + 32 * i;
      int c = tid & 7;
      float4 wv = *(const float4*)(Wsel + (size_t)row * K + k0 + c * 4);
      bf16x4v hi, lo;
      float vv[4] = {wv.x, wv.y, wv.z, wv.w};
#pragma unroll
      for (int e = 0; e < 4; ++e) {
        unsigned short h = f2b(vv[e]);
        hi[e] = (short)h;
        lo[e] = (short)f2b(vv[e] - b2f(h));
      }
      *(bf16x4v*)&sb_hi[row][c * 4] = hi;
      *(bf16x4v*)&sb_lo[row][c * 4] = lo;
    }
    // ---- stage activation tile 128x32 ----
    if constexpr (MODE == 0) {
      const float* X = (const float*)Xp;
#pragma unroll
      for (int i = 0; i < 4; ++i) {
        int row = (tid >> 3) + 32 * i;
        int c = tid & 7;
        float4 xv = *(const float4*)(X + (size_t)(m0 + row) * K + k0 + c * 4);
        bf16x4v hi, lo;
        float vv[4] = {xv.x, xv.y, xv.z, xv.w};
#pragma unroll
        for (int e = 0; e < 4; ++e) {
          unsigned short h = f2b(vv[e]);
          hi[e] = (short)h;
          lo[e] = (short)f2b(vv[e] - b2f(h));
        }
        *(bf16x4v*)&sa_hi[row][c * 4] = hi;
        *(bf16x4v*)&sa_lo[row][c * 4] = lo;
      }
    } else {
      const unsigned short* X = (const unsigned short*)Xp;
#pragma unroll
      for (int i = 0; i < 2; ++i) {
        int row = (tid >> 2) + 64 * i;
        int c = tid & 3;
        *(bf16x8*)&sa_hi[row][c * 8] =
            *(const bf16x8*)(X + (size_t)(m0 + row) * K + k0 + c * 8);
      }
    }
    __syncthreads();
    // ---- fragments + MFMA ----
    bf16x8 ah[4], al[4], bh[4], bl[4];
#pragma unroll
    for (int mi = 0; mi < 4; ++mi) {
      ah[mi] = *(const bf16x8*)&sa_hi[wm * 64 + mi * 16 + r16][g * 8];
      if constexpr (MODE == 0)
        al[mi] = *(const bf16x8*)&sa_lo[wm * 64 + mi * 16 + r16][g * 8];
    }
#pragma unroll
    for (int ni = 0; ni < 4; ++ni) {
      bh[ni] = *(const bf16x8*)&sb_hi[wn * 64 + ni * 16 + r16][g * 8];
      bl[ni] = *(const bf16x8*)&sb_lo[wn * 64 + ni * 16 + r16][g * 8];
    }
#pragma unroll
    for (int mi = 0; mi < 4; ++mi)
#pragma unroll
      for (int ni = 0; ni < 4; ++ni) {
        acc[mi][ni] = __builtin_amdgcn_mfma_f32_16x16x32_bf16(ah[mi], bh[ni], acc[mi][ni], 0, 0, 0);
        acc[mi][ni] = __builtin_amdgcn_mfma_f32_16x16x32_bf16(ah[mi], bl[ni], acc[mi][ni], 0, 0, 0);
        if constexpr (MODE == 0)
          acc[mi][ni] = __builtin_amdgcn_mfma_f32_16x16x32_bf16(al[mi], bh[ni], acc[mi][ni], 0, 0, 0);
      }
  }
  // ---- epilogue: D[m-local = 4g+r][n-local = r16] per (mi,ni) ----
  if constexpr (MODE == 0) {
    if (n0 < 768) {
      unsigned short* ko = (unsigned short*)out0;
#pragma unroll
      for (int mi = 0; mi < 4; ++mi)
#pragma unroll
        for (int ni = 0; ni < 4; ++ni)
#pragma unroll
          for (int r = 0; r < 4; ++r) {
            int m = m0 + wm * 64 + mi * 16 + g * 4 + r;
            int n = n0 + wn * 64 + ni * 16 + r16;
            int bb = m >> 10, tt = m & 1023, h = n >> 6, d = n & 63;
            ko[(((size_t)(bb * NH + h)) * T + tt) * HS + d] = f2b(acc[mi][ni][r]);
          }
    } else {
      unsigned short* lo_ = (unsigned short*)out1;
#pragma unroll
      for (int mi = 0; mi < 4; ++mi)
#pragma unroll
        for (int ni = 0; ni < 4; ++ni)
#pragma unroll
          for (int r = 0; r < 4; ++r) {
            int m = m0 + wm * 64 + mi * 16 + g * 4 + r;
            int n = n0 + wn * 64 + ni * 16 + r16;
            lo_[(size_t)m * 768 + (n - 768)] = f2b(acc[mi][ni][r]);
          }
    }
  } else {
    float* oo = (float*)out0;
#pragma unroll
    for (int mi = 0; mi < 4; ++mi)
#pragma unroll
      for (int ni = 0; ni < 4; ++ni)
#pragma unroll
        for (int r = 0; r < 4; ++r) {
          int m = m0 + wm * 64 + mi * 16 + g * 4 + r;
          int n = n0 + wn * 64 + ni * 16 + r16;
          oo[(size_t)m * 768 + n] = acc[mi][ni][r];
        }
  }
}

// ---------------- v mixing + normalize (bf16 in -> bf16 head-major out) ----
__global__ __launch_bounds__(256) void vcompute(const unsigned short* __restrict__ lin,
                                                const float* __restrict__ coef,
                                                const float* __restrict__ vbeta,
                                                unsigned short* __restrict__ vout) {
  int w = (blockIdx.x * 256 + threadIdx.x) >> 6;
  int lane = threadIdx.x & 63;
  int t = w % T;
  int h = (w / T) % NH;
  int b = w / (T * NH);
  float c = coef[h];
  float vh = b2f(lin[((size_t)(b * T + t)) * C + h * HS + lane]);
  float vs = (t + 1 < T) ? b2f(lin[((size_t)(b * T + t + 1)) * C + h * HS + lane]) : 0.0f;
  float v = vs * (1.0f - c) + vh * c;
  float ss = v * v;
#pragma unroll
  for (int off = 1; off < 64; off <<= 1) ss += __shfl_xor(ss, off);
  float scale = rsqrtf(ss) * expf(vbeta[h] * ESCALE);
  vout[(((size_t)(b * NH + h) * T + t) * HS) + lane] = f2b(v * scale);
}

// ============ EMA as two-level chunked scan (768 independent waves) ========
// The L2-norm does not feed the recurrence, so scan and norm decouple.
// K1: per (bh, 64-step chunk) local scan from zero -> chunk end-state.
__global__ __launch_bounds__(64) void ema_scan(const unsigned short* __restrict__ kb,
                                               const float* __restrict__ lkb,
                                               float* __restrict__ ends) {
  const int bx = blockIdx.x;
  const int bh = bx >> 4, ch = bx & (NCH - 1);
  const int d = threadIdx.x;
  const int h = bh % NH;
  const float lam = fabsf(lkb[h]) * ESCALE;
  const float a = expf(-lam), wf = 1.0f - a;
  const unsigned short* p = kb + (size_t)bh * T * HS + d;
  const int t0 = ch * ECH;
  float s = 0.0f;
#pragma unroll 8
  for (int t = t0; t < t0 + ECH; ++t) s = a * s + wf * b2f(p[(size_t)t * HS]);
  ends[((size_t)bh * NCH + ch) * HS + d] = s;
}

// K2: combine carries (a^64-weighted), re-scan 64 steps with exact init,
// normalize rows (batched 8 wide for shuffle-tree ILP), scale by kb, write.
__global__ __launch_bounds__(64) void ema_apply(unsigned short* __restrict__ kb,
                                                const float* __restrict__ lkb,
                                                const float* __restrict__ kbeta,
                                                const float* __restrict__ ends) {
  const int bx = blockIdx.x;
  const int bh = bx >> 4, ch = bx & (NCH - 1);
  const int d = threadIdx.x;
  const int h = bh % NH;
  const float lam = fabsf(lkb[h]) * ESCALE;
  const float a = expf(-lam), wf = 1.0f - a;
  const float a64 = expf(-lam * (float)ECH);
  const float kbs = expf(fminf(kbeta[h] * ESCALE, KBUP));
  unsigned short* p = kb + (size_t)bh * T * HS + d;
  float carry = 0.0f;
  for (int c = 0; c < ch; ++c)
    carry = a64 * carry + ends[((size_t)bh * NCH + c) * HS + d];
  float s = carry;
  const int t0 = ch * ECH;
  for (int tb = 0; tb < ECH; tb += 8) {
    float sr[8], q[8];
#pragma unroll
    for (int u = 0; u < 8; ++u) {
      s = a * s + wf * b2f(p[(size_t)(t0 + tb + u) * HS]);
      sr[u] = s;
    }
#pragma unroll
    for (int u = 0; u < 8; ++u) q[u] = sr[u] * sr[u];
#pragma unroll
    for (int off = 1; off < 64; off <<= 1)
#pragma unroll
      for (int u = 0; u < 8; ++u) q[u] += __shfl_xor(q[u], off);
#pragma unroll
    for (int u = 0; u < 8; ++u)
      p[(size_t)(t0 + tb + u) * HS] = f2b(sr[u] * rsqrtf(q[u]) * kbs);
  }
}

// ---------------- MFMA flash attention (bf16 K/V, swapped-QK^T) ------------
__global__ __launch_bounds__(256) void attn_mfma(const unsigned short* __restrict__ Km,
                                                 const unsigned short* __restrict__ Vm,
                                                 unsigned short* __restrict__ Y) {
  const int bid = blockIdx.x;
  const int qt = 15 - (bid / (B * NH));  // heavy q-tiles first
  const int bh = bid % (B * NH);
  const int b = bh / NH, h = bh % NH;
  const int qi0 = qt * 64;
  const short* Kb = (const short*)(Km + (size_t)bh * T * HS);
  const short* Vb = (const short*)(Vm + (size_t)bh * T * HS);
  __shared__ short kt[64 * 72];       // K-tile row-major [j][d]
  __shared__ short vt[64 * 72];       // V-tile transposed [d][j]
  __shared__ short pl[4 * 16 * 72];   // per-wave P [i][j]
  const int tid = threadIdx.x;
  const int w = tid >> 6, lane = tid & 63;
  const int qr = lane & 15, qg = lane >> 4;

  bf16x8 qf0 = *(const bf16x8*)(Kb + (size_t)(qi0 + w * 16 + qr) * HS + qg * 8);
  bf16x8 qf1 = *(const bf16x8*)(Kb + (size_t)(qi0 + w * 16 + qr) * HS + qg * 8 + 32);

  f32x4 o[4];
#pragma unroll
  for (int db = 0; db < 4; ++db) o[db] = (f32x4){0.f, 0.f, 0.f, 0.f};
  float m_st = -INFINITY, l_st = 0.0f;

  const int njt = qt + 1;
  for (int jt = 0; jt < njt; ++jt) {
    const int j0 = jt * 64;
    __syncthreads();
#pragma unroll
    for (int it = 0; it < 2; ++it) {
      int idx = tid + it * 256;
      int row = idx >> 3, ch = idx & 7;
      *(bf16x8*)&kt[row * 72 + ch * 8] =
          *(const bf16x8*)(Kb + (size_t)(j0 + row) * HS + ch * 8);
      int vj = idx & 63, vd0 = (idx >> 6) * 8;
      bf16x8 vv = *(const bf16x8*)(Vb + (size_t)(j0 + vj) * HS + vd0);
#pragma unroll
      for (int e = 0; e < 8; ++e) vt[(vd0 + e) * 72 + vj] = vv[e];
    }
    __syncthreads();
    f32x4 st[4];
#pragma unroll
    for (int jb = 0; jb < 4; ++jb) st[jb] = (f32x4){0.f, 0.f, 0.f, 0.f};
#pragma unroll
    for (int jb = 0; jb < 4; ++jb) {
      bf16x8 kf0 = *(const bf16x8*)&kt[(qr + 16 * jb) * 72 + qg * 8];
      bf16x8 kf1 = *(const bf16x8*)&kt[(qr + 16 * jb) * 72 + qg * 8 + 32];
      st[jb] = __builtin_amdgcn_mfma_f32_16x16x32_bf16(kf0, qf0, st[jb], 0, 0, 0);
      st[jb] = __builtin_amdgcn_mfma_f32_16x16x32_bf16(kf1, qf1, st[jb], 0, 0, 0);
    }
    if (jt == njt - 1) {
      const int ii = qi0 + w * 16 + qr;
#pragma unroll
      for (int jb = 0; jb < 4; ++jb)
#pragma unroll
        for (int r = 0; r < 4; ++r) {
          int jj = j0 + 16 * jb + qg * 4 + r;
          if (jj >= ii) st[jb][r] = -INFINITY;
        }
    }
    float rm = -INFINITY;
#pragma unroll
    for (int jb = 0; jb < 4; ++jb)
#pragma unroll
      for (int r = 0; r < 4; ++r) rm = fmaxf(rm, st[jb][r]);
    rm = fmaxf(rm, __shfl_xor(rm, 16));
    rm = fmaxf(rm, __shfl_xor(rm, 32));
    float mnew = fmaxf(m_st, rm);
    float scale = (mnew == -INFINITY) ? 1.0f : __expf(m_st - mnew);
    float p[4][4];
    float rs = 0.0f;
#pragma unroll
    for (int jb = 0; jb < 4; ++jb)
#pragma unroll
      for (int r = 0; r < 4; ++r) {
        float pv = (st[jb][r] == -INFINITY) ? 0.0f : __expf(st[jb][r] - mnew);
        p[jb][r] = pv;
        rs += pv;
      }
    rs += __shfl_xor(rs, 16);
    rs += __shfl_xor(rs, 32);
    l_st = l_st * scale + rs;
    m_st = mnew;
#pragma unroll
    for (int db = 0; db < 4; ++db) o[db] *= scale;
#pragma unroll
    for (int jb = 0; jb < 4; ++jb) {
      bf16x4v pw;
#pragma unroll
      for (int r = 0; r < 4; ++r) pw[r] = (short)f2b(p[jb][r]);
      *(bf16x4v*)&pl[w * 1152 + qr * 72 + jb * 16 + qg * 4] = pw;
    }
#pragma unroll
    for (int ks = 0; ks < 2; ++ks) {
      bf16x8 pf = *(const bf16x8*)&pl[w * 1152 + qr * 72 + ks * 32 + qg * 8];
#pragma unroll
      for (int db = 0; db < 4; ++db) {
        bf16x8 vf = *(const bf16x8*)&vt[(qr + 16 * db) * 72 + qg * 8 + ks * 32];
        o[db] = __builtin_amdgcn_mfma_f32_16x16x32_bf16(vf, pf, o[db], 0, 0, 0);
      }
    }
  }
  float inv = (l_st > 0.0f) ? 1.0f / l_st : 0.0f;
#pragma unroll
  for (int db = 0; db < 4; ++db) {
    bf16x4v yv;
#pragma unroll
    for (int r = 0; r < 4; ++r) yv[r] = (short)f2b(o[db][r] * inv);
    *(bf16x4v*)(Y + (size_t)(b * T + qi0 + w * 16 + qr) * C + h * HS + db * 16 + qg * 4) = yv;
  }
}

extern "C" void kernel_launch(void* const* d_in, const int* in_sizes, int n_in,
                              void* d_out, int out_size, void* d_ws, size_t ws_size,
                              hipStream_t stream) {
  const float* x = (const float*)d_in[0];
  const float* conv_w = (const float*)d_in[1];
  const float* lin_w = (const float*)d_in[2];
  const float* coef = (const float*)d_in[3];
  const float* lkb = (const float*)d_in[4];
  const float* kbeta = (const float*)d_in[5];
  const float* vbeta = (const float*)d_in[6];
  const float* proj_w = (const float*)d_in[7];

  // ws = 2*NE bf16 = 12.58 MB (proven-safe footprint).
  //   A = ws[0:NE)  : lin bf16 (tok-major), later y bf16 (tok-major)
  //   B = ws[NE:2NE): k bf16 (head-major)
  // d_out: v bf16 in bytes [0,2NE); EMA chunk-ends scratch (196 KB) in bytes
  // [2NE,...) — both dead before the final GEMM overwrites d_out with fp32.
  const size_t NE = (size_t)B * T * C;
  unsigned short* abuf = (unsigned short*)d_ws;  // lin, then y
  unsigned short* kbuf = abuf + NE;              // k
  unsigned short* vbuf = (unsigned short*)d_out; // v (scratch phase)
  float* ends = (float*)(vbuf + NE);             // [B*NH][NCH][HS] fp32

  gemm_mfma<0><<<dim3(32, 12), 256, 0, stream>>>(x, conv_w, lin_w, kbuf, abuf);
  vcompute<<<(B * NH * T) / 4, 256, 0, stream>>>(abuf, coef, vbeta, vbuf);
  ema_scan<<<B * NH * NCH, 64, 0, stream>>>(kbuf, lkb, ends);
  ema_apply<<<B * NH * NCH, 64, 0, stream>>>(kbuf, lkb, kbeta, ends);
  attn_mfma<<<T / 64 * B * NH, 256, 0, stream>>>(kbuf, vbuf, abuf);
  gemm_mfma<1><<<dim3(32, 6), 256, 0, stream>>>(abuf, proj_w, nullptr, d_out, nullptr);
}

// Round 14
// 205.183 us; speedup vs baseline: 2.9058x; 1.0431x over previous
//
#include <hip/hip_runtime.h>
#include <math.h>

#define B 4
#define T 1024
#define C 768
#define NH 12
#define HS 64
#define ESCALE 10.0f
#define KBUP 5.0f
#define ECH 64
#define NCH (T / ECH)

typedef short bf16x8 __attribute__((ext_vector_type(8)));
typedef short bf16x4v __attribute__((ext_vector_type(4)));
typedef float f32x4 __attribute__((ext_vector_type(4)));

__device__ inline unsigned short f2b(float f) {
  union { float f; unsigned int u; } x;
  x.f = f;
  unsigned int r = (x.u + 0x7FFF + ((x.u >> 16) & 1)) >> 16;
  return (unsigned short)r;
}
__device__ inline float b2f(unsigned short u) {
  union { float f; unsigned int i; } x;
  x.i = ((unsigned int)u) << 16;
  return x.f;
}

// ---------------- x -> (hi, lo) bf16 split, done ONCE (was 12x in-GEMM) ----
__global__ __launch_bounds__(256) void split_x(const float* __restrict__ x,
                                               unsigned short* __restrict__ xhi,
                                               unsigned short* __restrict__ xlo) {
  const size_t NEl = (size_t)B * T * C;
  size_t i = ((size_t)blockIdx.x * 256 + threadIdx.x) * 4;
  const size_t stride = (size_t)gridDim.x * 256 * 4;
  for (; i < NEl; i += stride) {
    float4 v = *(const float4*)(x + i);
    float vv[4] = {v.x, v.y, v.z, v.w};
    ushort4 hi, lo;
    unsigned short* hp = (unsigned short*)&hi;
    unsigned short* lp = (unsigned short*)&lo;
#pragma unroll
    for (int e = 0; e < 4; ++e) {
      unsigned short h = f2b(vv[e]);
      hp[e] = h;
      lp[e] = f2b(vv[e] - b2f(h));
    }
    *(ushort4*)(xhi + i) = hi;
    *(ushort4*)(xlo + i) = lo;
  }
}

// ================= MFMA GEMM: out = X @ W^T (split-bf16) ==================
// BM=64, BN=128, BK=32; 4 waves, each wave owns 32 cols x 64 rows.
// MODE 0: A = (xhi,xlo) pre-split bf16 [4096][768]; W0=conv_w, W1=lin_w; N=1536.
//         n<768 -> out0 = k bf16 head-major; n>=768 -> out1 = lin bf16 tok-major.
//         acc += Ah*Bh + Ah*Bl + Al*Bh  (same order as before -> bit-identical)
// MODE 1: A = y bf16 (no lo); W0=proj_w; N=768; out0 fp32 token-major.
template <int MODE>
__global__ __launch_bounds__(256) void gemm_mfma(const unsigned short* __restrict__ Xhi,
                                                 const unsigned short* __restrict__ Xlo,
                                                 const float* __restrict__ W0,
                                                 const float* __restrict__ W1,
                                                 void* __restrict__ out0,
                                                 void* __restrict__ out1) {
  const int K = 768;
  __shared__ short sa_hi[64][40];
  __shared__ short sa_lo[(MODE == 0) ? 64 : 1][40];
  __shared__ short sb_hi[128][40];
  __shared__ short sb_lo[128][40];
  const int tid = threadIdx.x;
  const int m0 = blockIdx.x * 64;
  const int n0 = blockIdx.y * 128;
  const int w = tid >> 6, lane = tid & 63;
  const int r16 = lane & 15, g = lane >> 4;
  const int arow = tid >> 2, ac = (tid & 3) * 8;   // A stage: 64 rows x 4 chunks
  const int wrow = tid >> 3, wc = (tid & 7) * 4;   // W stage: 32 rows/iter x 8 chunks
  const float* Wsel = (MODE == 0 && n0 >= 768) ? (W1 + (size_t)(n0 - 768) * K)
                                               : (W0 + (size_t)n0 * K);
  f32x4 acc[4][2];
#pragma unroll
  for (int mi = 0; mi < 4; ++mi)
#pragma unroll
    for (int ni = 0; ni < 2; ++ni) acc[mi][ni] = (f32x4){0.f, 0.f, 0.f, 0.f};

  for (int k0 = 0; k0 < K; k0 += 32) {
    __syncthreads();
    // ---- stage W tile 128x32, split hi/lo (VALU) ----
#pragma unroll
    for (int i = 0; i < 4; ++i) {
      int row = wrow + 32 * i;
      float4 wv = *(const float4*)(Wsel + (size_t)row * K + k0 + wc);
      bf16x4v hi, lo;
      float vv[4] = {wv.x, wv.y, wv.z, wv.w};
#pragma unroll
      for (int e = 0; e < 4; ++e) {
        unsigned short h = f2b(vv[e]);
        hi[e] = (short)h;
        lo[e] = (short)f2b(vv[e] - b2f(h));
      }
      *(bf16x4v*)&sb_hi[row][wc] = hi;
      *(bf16x4v*)&sb_lo[row][wc] = lo;
    }
    // ---- stage A tile 64x32: pure bf16 vector copy, zero VALU ----
    *(bf16x8*)&sa_hi[arow][ac] =
        *(const bf16x8*)(Xhi + (size_t)(m0 + arow) * K + k0 + ac);
    if constexpr (MODE == 0) {
      *(bf16x8*)&sa_lo[arow][ac] =
          *(const bf16x8*)(Xlo + (size_t)(m0 + arow) * K + k0 + ac);
    }
    __syncthreads();
    // ---- fragments + MFMA ----
    bf16x8 ah[4], al[4], bh[2], bl[2];
#pragma unroll
    for (int mi = 0; mi < 4; ++mi) {
      ah[mi] = *(const bf16x8*)&sa_hi[mi * 16 + r16][g * 8];
      if constexpr (MODE == 0)
        al[mi] = *(const bf16x8*)&sa_lo[mi * 16 + r16][g * 8];
    }
#pragma unroll
    for (int ni = 0; ni < 2; ++ni) {
      bh[ni] = *(const bf16x8*)&sb_hi[w * 32 + ni * 16 + r16][g * 8];
      bl[ni] = *(const bf16x8*)&sb_lo[w * 32 + ni * 16 + r16][g * 8];
    }
#pragma unroll
    for (int mi = 0; mi < 4; ++mi)
#pragma unroll
      for (int ni = 0; ni < 2; ++ni) {
        acc[mi][ni] = __builtin_amdgcn_mfma_f32_16x16x32_bf16(ah[mi], bh[ni], acc[mi][ni], 0, 0, 0);
        acc[mi][ni] = __builtin_amdgcn_mfma_f32_16x16x32_bf16(ah[mi], bl[ni], acc[mi][ni], 0, 0, 0);
        if constexpr (MODE == 0)
          acc[mi][ni] = __builtin_amdgcn_mfma_f32_16x16x32_bf16(al[mi], bh[ni], acc[mi][ni], 0, 0, 0);
      }
  }
  // ---- epilogue: D row (A) = g*4+r, col (B) = r16 ----
  if constexpr (MODE == 0) {
    if (n0 < 768) {
      unsigned short* ko = (unsigned short*)out0;
#pragma unroll
      for (int mi = 0; mi < 4; ++mi)
#pragma unroll
        for (int ni = 0; ni < 2; ++ni)
#pragma unroll
          for (int r = 0; r < 4; ++r) {
            int m = m0 + mi * 16 + g * 4 + r;
            int n = n0 + w * 32 + ni * 16 + r16;
            int bb = m >> 10, tt = m & 1023, h = n >> 6, d = n & 63;
            ko[(((size_t)(bb * NH + h)) * T + tt) * HS + d] = f2b(acc[mi][ni][r]);
          }
    } else {
      unsigned short* lo_ = (unsigned short*)out1;
#pragma unroll
      for (int mi = 0; mi < 4; ++mi)
#pragma unroll
        for (int ni = 0; ni < 2; ++ni)
#pragma unroll
          for (int r = 0; r < 4; ++r) {
            int m = m0 + mi * 16 + g * 4 + r;
            int n = n0 + w * 32 + ni * 16 + r16;
            lo_[(size_t)m * 768 + (n - 768)] = f2b(acc[mi][ni][r]);
          }
    }
  } else {
    float* oo = (float*)out0;
#pragma unroll
    for (int mi = 0; mi < 4; ++mi)
#pragma unroll
      for (int ni = 0; ni < 2; ++ni)
#pragma unroll
        for (int r = 0; r < 4; ++r) {
          int m = m0 + mi * 16 + g * 4 + r;
          int n = n0 + w * 32 + ni * 16 + r16;
          oo[(size_t)m * 768 + n] = acc[mi][ni][r];
        }
  }
}

// ---------------- v mixing + normalize (bf16 in -> bf16 head-major out) ----
__global__ __launch_bounds__(256) void vcompute(const unsigned short* __restrict__ lin,
                                                const float* __restrict__ coef,
                                                const float* __restrict__ vbeta,
                                                unsigned short* __restrict__ vout) {
  int w = (blockIdx.x * 256 + threadIdx.x) >> 6;
  int lane = threadIdx.x & 63;
  int t = w % T;
  int h = (w / T) % NH;
  int b = w / (T * NH);
  float c = coef[h];
  float vh = b2f(lin[((size_t)(b * T + t)) * C + h * HS + lane]);
  float vs = (t + 1 < T) ? b2f(lin[((size_t)(b * T + t + 1)) * C + h * HS + lane]) : 0.0f;
  float v = vs * (1.0f - c) + vh * c;
  float ss = v * v;
#pragma unroll
  for (int off = 1; off < 64; off <<= 1) ss += __shfl_xor(ss, off);
  float scale = rsqrtf(ss) * expf(vbeta[h] * ESCALE);
  vout[(((size_t)(b * NH + h) * T + t) * HS) + lane] = f2b(v * scale);
}

// ============ EMA as two-level chunked scan (768 independent waves) ========
__global__ __launch_bounds__(64) void ema_scan(const unsigned short* __restrict__ kb,
                                               const float* __restrict__ lkb,
                                               float* __restrict__ ends) {
  const int bx = blockIdx.x;
  const int bh = bx >> 4, ch = bx & (NCH - 1);
  const int d = threadIdx.x;
  const int h = bh % NH;
  const float lam = fabsf(lkb[h]) * ESCALE;
  const float a = expf(-lam), wf = 1.0f - a;
  const unsigned short* p = kb + (size_t)bh * T * HS + d;
  const int t0 = ch * ECH;
  float s = 0.0f;
#pragma unroll 8
  for (int t = t0; t < t0 + ECH; ++t) s = a * s + wf * b2f(p[(size_t)t * HS]);
  ends[((size_t)bh * NCH + ch) * HS + d] = s;
}

__global__ __launch_bounds__(64) void ema_apply(unsigned short* __restrict__ kb,
                                                const float* __restrict__ lkb,
                                                const float* __restrict__ kbeta,
                                                const float* __restrict__ ends) {
  const int bx = blockIdx.x;
  const int bh = bx >> 4, ch = bx & (NCH - 1);
  const int d = threadIdx.x;
  const int h = bh % NH;
  const float lam = fabsf(lkb[h]) * ESCALE;
  const float a = expf(-lam), wf = 1.0f - a;
  const float a64 = expf(-lam * (float)ECH);
  const float kbs = expf(fminf(kbeta[h] * ESCALE, KBUP));
  unsigned short* p = kb + (size_t)bh * T * HS + d;
  float carry = 0.0f;
  for (int c = 0; c < ch; ++c)
    carry = a64 * carry + ends[((size_t)bh * NCH + c) * HS + d];
  float s = carry;
  const int t0 = ch * ECH;
  for (int tb = 0; tb < ECH; tb += 8) {
    float sr[8], q[8];
#pragma unroll
    for (int u = 0; u < 8; ++u) {
      s = a * s + wf * b2f(p[(size_t)(t0 + tb + u) * HS]);
      sr[u] = s;
    }
#pragma unroll
    for (int u = 0; u < 8; ++u) q[u] = sr[u] * sr[u];
#pragma unroll
    for (int off = 1; off < 64; off <<= 1)
#pragma unroll
      for (int u = 0; u < 8; ++u) q[u] += __shfl_xor(q[u], off);
#pragma unroll
    for (int u = 0; u < 8; ++u)
      p[(size_t)(t0 + tb + u) * HS] = f2b(sr[u] * rsqrtf(q[u]) * kbs);
  }
}

// ---------------- MFMA flash attention (bf16 K/V, swapped-QK^T) ------------
__global__ __launch_bounds__(256) void attn_mfma(const unsigned short* __restrict__ Km,
                                                 const unsigned short* __restrict__ Vm,
                                                 unsigned short* __restrict__ Y) {
  const int bid = blockIdx.x;
  const int qt = 15 - (bid / (B * NH));  // heavy q-tiles first
  const int bh = bid % (B * NH);
  const int b = bh / NH, h = bh % NH;
  const int qi0 = qt * 64;
  const short* Kb = (const short*)(Km + (size_t)bh * T * HS);
  const short* Vb = (const short*)(Vm + (size_t)bh * T * HS);
  __shared__ short kt[64 * 72];
  __shared__ short vt[64 * 72];
  __shared__ short pl[4 * 16 * 72];
  const int tid = threadIdx.x;
  const int w = tid >> 6, lane = tid & 63;
  const int qr = lane & 15, qg = lane >> 4;

  bf16x8 qf0 = *(const bf16x8*)(Kb + (size_t)(qi0 + w * 16 + qr) * HS + qg * 8);
  bf16x8 qf1 = *(const bf16x8*)(Kb + (size_t)(qi0 + w * 16 + qr) * HS + qg * 8 + 32);

  f32x4 o[4];
#pragma unroll
  for (int db = 0; db < 4; ++db) o[db] = (f32x4){0.f, 0.f, 0.f, 0.f};
  float m_st = -INFINITY, l_st = 0.0f;

  const int njt = qt + 1;
  for (int jt = 0; jt < njt; ++jt) {
    const int j0 = jt * 64;
    __syncthreads();
#pragma unroll
    for (int it = 0; it < 2; ++it) {
      int idx = tid + it * 256;
      int row = idx >> 3, ch = idx & 7;
      *(bf16x8*)&kt[row * 72 + ch * 8] =
          *(const bf16x8*)(Kb + (size_t)(j0 + row) * HS + ch * 8);
      int vj = idx & 63, vd0 = (idx >> 6) * 8;
      bf16x8 vv = *(const bf16x8*)(Vb + (size_t)(j0 + vj) * HS + vd0);
#pragma unroll
      for (int e = 0; e < 8; ++e) vt[(vd0 + e) * 72 + vj] = vv[e];
    }
    __syncthreads();
    f32x4 st[4];
#pragma unroll
    for (int jb = 0; jb < 4; ++jb) st[jb] = (f32x4){0.f, 0.f, 0.f, 0.f};
#pragma unroll
    for (int jb = 0; jb < 4; ++jb) {
      bf16x8 kf0 = *(const bf16x8*)&kt[(qr + 16 * jb) * 72 + qg * 8];
      bf16x8 kf1 = *(const bf16x8*)&kt[(qr + 16 * jb) * 72 + qg * 8 + 32];
      st[jb] = __builtin_amdgcn_mfma_f32_16x16x32_bf16(kf0, qf0, st[jb], 0, 0, 0);
      st[jb] = __builtin_amdgcn_mfma_f32_16x16x32_bf16(kf1, qf1, st[jb], 0, 0, 0);
    }
    if (jt == njt - 1) {
      const int ii = qi0 + w * 16 + qr;
#pragma unroll
      for (int jb = 0; jb < 4; ++jb)
#pragma unroll
        for (int r = 0; r < 4; ++r) {
          int jj = j0 + 16 * jb + qg * 4 + r;
          if (jj >= ii) st[jb][r] = -INFINITY;
        }
    }
    float rm = -INFINITY;
#pragma unroll
    for (int jb = 0; jb < 4; ++jb)
#pragma unroll
      for (int r = 0; r < 4; ++r) rm = fmaxf(rm, st[jb][r]);
    rm = fmaxf(rm, __shfl_xor(rm, 16));
    rm = fmaxf(rm, __shfl_xor(rm, 32));
    float mnew = fmaxf(m_st, rm);
    float scale = (mnew == -INFINITY) ? 1.0f : __expf(m_st - mnew);
    float p[4][4];
    float rs = 0.0f;
#pragma unroll
    for (int jb = 0; jb < 4; ++jb)
#pragma unroll
      for (int r = 0; r < 4; ++r) {
        float pv = (st[jb][r] == -INFINITY) ? 0.0f : __expf(st[jb][r] - mnew);
        p[jb][r] = pv;
        rs += pv;
      }
    rs += __shfl_xor(rs, 16);
    rs += __shfl_xor(rs, 32);
    l_st = l_st * scale + rs;
    m_st = mnew;
#pragma unroll
    for (int db = 0; db < 4; ++db) o[db] *= scale;
#pragma unroll
    for (int jb = 0; jb < 4; ++jb) {
      bf16x4v pw;
#pragma unroll
      for (int r = 0; r < 4; ++r) pw[r] = (short)f2b(p[jb][r]);
      *(bf16x4v*)&pl[w * 1152 + qr * 72 + jb * 16 + qg * 4] = pw;
    }
#pragma unroll
    for (int ks = 0; ks < 2; ++ks) {
      bf16x8 pf = *(const bf16x8*)&pl[w * 1152 + qr * 72 + ks * 32 + qg * 8];
#pragma unroll
      for (int db = 0; db < 4; ++db) {
        bf16x8 vf = *(const bf16x8*)&vt[(qr + 16 * db) * 72 + qg * 8 + ks * 32];
        o[db] = __builtin_amdgcn_mfma_f32_16x16x32_bf16(vf, pf, o[db], 0, 0, 0);
      }
    }
  }
  float inv = (l_st > 0.0f) ? 1.0f / l_st : 0.0f;
#pragma unroll
  for (int db = 0; db < 4; ++db) {
    bf16x4v yv;
#pragma unroll
    for (int r = 0; r < 4; ++r) yv[r] = (short)f2b(o[db][r] * inv);
    *(bf16x4v*)(Y + (size_t)(b * T + qi0 + w * 16 + qr) * C + h * HS + db * 16 + qg * 4) = yv;
  }
}

extern "C" void kernel_launch(void* const* d_in, const int* in_sizes, int n_in,
                              void* d_out, int out_size, void* d_ws, size_t ws_size,
                              hipStream_t stream) {
  const float* x = (const float*)d_in[0];
  const float* conv_w = (const float*)d_in[1];
  const float* lin_w = (const float*)d_in[2];
  const float* coef = (const float*)d_in[3];
  const float* lkb = (const float*)d_in[4];
  const float* kbeta = (const float*)d_in[5];
  const float* vbeta = (const float*)d_in[6];
  const float* proj_w = (const float*)d_in[7];

  // ws = 2*NE bf16 = 12.58 MB (proven-safe): abuf (lin -> y) | kbuf (k).
  // d_out timeline: [xhi|xlo] bf16 (phase 1, exactly 12.58 MB) -> v bf16 over
  // dead xhi + ends over dead xlo -> final fp32 out overwrites everything.
  const size_t NE = (size_t)B * T * C;
  unsigned short* abuf = (unsigned short*)d_ws;   // lin, then y
  unsigned short* kbuf = abuf + NE;               // k
  unsigned short* xhi = (unsigned short*)d_out;   // phase-1 scratch
  unsigned short* xlo = xhi + NE;
  unsigned short* vbuf = (unsigned short*)d_out;  // v (over dead xhi)
  float* ends = (float*)(vbuf + NE);              // over dead xlo (196 KB)

  split_x<<<2048, 256, 0, stream>>>(x, xhi, xlo);
  gemm_mfma<0><<<dim3(64, 12), 256, 0, stream>>>(xhi, xlo, conv_w, lin_w, kbuf, abuf);
  vcompute<<<(B * NH * T) / 4, 256, 0, stream>>>(abuf, coef, vbeta, vbuf);
  ema_scan<<<B * NH * NCH, 64, 0, stream>>>(kbuf, lkb, ends);
  ema_apply<<<B * NH * NCH, 64, 0, stream>>>(kbuf, lkb, kbeta, ends);
  attn_mfma<<<T / 64 * B * NH, 256, 0, stream>>>(kbuf, vbuf, abuf);
  gemm_mfma<1><<<dim3(64, 6), 256, 0, stream>>>(abuf, abuf, proj_w, nullptr, d_out, nullptr);
}

// Round 15
// 201.085 us; speedup vs baseline: 2.9650x; 1.0204x over previous
//
#include <hip/hip_runtime.h>
#include <math.h>

#define B 4
#define T 1024
#define C 768
#define NH 12
#define HS 64
#define ESCALE 10.0f
#define KBUP 5.0f
#define ECH 64
#define NCH (T / ECH)
#define WE (768 * 768)

typedef short bf16x8 __attribute__((ext_vector_type(8)));
typedef short bf16x4v __attribute__((ext_vector_type(4)));
typedef float f32x4 __attribute__((ext_vector_type(4)));

__device__ inline unsigned short f2b(float f) {
  union { float f; unsigned int u; } x;
  x.f = f;
  unsigned int r = (x.u + 0x7FFF + ((x.u >> 16) & 1)) >> 16;
  return (unsigned short)r;
}
__device__ inline float b2f(unsigned short u) {
  union { float f; unsigned int i; } x;
  x.i = ((unsigned int)u) << 16;
  return x.f;
}

// -------- conv_w + lin_w -> (hi, lo) bf16, split ONCE (was 64x in-GEMM) ----
// dst layout: [Wc_hi WE | Wc_lo WE | Wl_hi WE | Wl_lo WE]
__global__ __launch_bounds__(256) void split_w(const float* __restrict__ wc,
                                               const float* __restrict__ wl,
                                               unsigned short* __restrict__ dst) {
  int i4 = (blockIdx.x * 256 + threadIdx.x) * 4;
  if (i4 >= 2 * WE) return;
  const float* src = (i4 < WE) ? (wc + i4) : (wl + (i4 - WE));
  unsigned short* hi = (i4 < WE) ? (dst + i4) : (dst + 2 * WE + (i4 - WE));
  unsigned short* lo = hi + WE;
  float4 v = *(const float4*)src;
  float vv[4] = {v.x, v.y, v.z, v.w};
  ushort4 h4, l4;
  unsigned short* hp = (unsigned short*)&h4;
  unsigned short* lp = (unsigned short*)&l4;
#pragma unroll
  for (int e = 0; e < 4; ++e) {
    unsigned short h = f2b(vv[e]);
    hp[e] = h;
    lp[e] = f2b(vv[e] - b2f(h));
  }
  *(ushort4*)hi = h4;
  *(ushort4*)lo = l4;
}

// ============ GEMM0: {k, lin} = x @ {conv_w, lin_w}^T (split-bf16) =========
// BM=64, BN=128, BK=32; 4 waves x (64 rows x 32 cols). A = x fp32 (in-kernel
// split, 64x32/blk); B = PRE-SPLIT bf16 (pure copy staging, zero VALU).
// acc += Ah*Bh + Ah*Bl + Al*Bh (same order as r14 -> bit-identical).
__global__ __launch_bounds__(256) void gemm0(const float* __restrict__ X,
                                             const unsigned short* __restrict__ wsp,
                                             unsigned short* __restrict__ kout,
                                             unsigned short* __restrict__ linout) {
  const int K = 768;
  __shared__ short sa_hi[64][40];
  __shared__ short sa_lo[64][40];
  __shared__ short sb_hi[128][40];
  __shared__ short sb_lo[128][40];
  const int tid = threadIdx.x;
  const int m0 = blockIdx.x * 64;
  const int n0 = blockIdx.y * 128;
  const int w = tid >> 6, lane = tid & 63;
  const int r16 = lane & 15, g = lane >> 4;
  const int row = tid >> 2, ac = (tid & 3) * 8;
  const unsigned short* Bhi;
  const unsigned short* Blo;
  int nr0;
  if (n0 < 768) { Bhi = wsp;          Blo = wsp + WE;     nr0 = n0; }
  else          { Bhi = wsp + 2 * WE; Blo = wsp + 3 * WE; nr0 = n0 - 768; }
  f32x4 acc[4][2];
#pragma unroll
  for (int mi = 0; mi < 4; ++mi)
#pragma unroll
    for (int ni = 0; ni < 2; ++ni) acc[mi][ni] = (f32x4){0.f, 0.f, 0.f, 0.f};

  for (int k0 = 0; k0 < K; k0 += 32) {
    __syncthreads();
    // ---- stage B 128x32 hi/lo: pure bf16 copies ----
#pragma unroll
    for (int i = 0; i < 2; ++i) {
      int br = row + i * 64;
      *(bf16x8*)&sb_hi[br][ac] =
          *(const bf16x8*)(Bhi + (size_t)(nr0 + br) * K + k0 + ac);
      *(bf16x8*)&sb_lo[br][ac] =
          *(const bf16x8*)(Blo + (size_t)(nr0 + br) * K + k0 + ac);
    }
    // ---- stage A 64x32: fp32 -> hi/lo split (only 64x32/blk) ----
    {
      const float* xp = X + (size_t)(m0 + row) * K + k0 + ac;
      float4 a0 = *(const float4*)xp;
      float4 a1 = *(const float4*)(xp + 4);
      float vv[8] = {a0.x, a0.y, a0.z, a0.w, a1.x, a1.y, a1.z, a1.w};
      bf16x8 hi, lo;
#pragma unroll
      for (int e = 0; e < 8; ++e) {
        unsigned short h = f2b(vv[e]);
        hi[e] = (short)h;
        lo[e] = (short)f2b(vv[e] - b2f(h));
      }
      *(bf16x8*)&sa_hi[row][ac] = hi;
      *(bf16x8*)&sa_lo[row][ac] = lo;
    }
    __syncthreads();
    // ---- fragments + MFMA ----
    bf16x8 ah[4], al[4], bh[2], bl[2];
#pragma unroll
    for (int mi = 0; mi < 4; ++mi) {
      ah[mi] = *(const bf16x8*)&sa_hi[mi * 16 + r16][g * 8];
      al[mi] = *(const bf16x8*)&sa_lo[mi * 16 + r16][g * 8];
    }
#pragma unroll
    for (int ni = 0; ni < 2; ++ni) {
      bh[ni] = *(const bf16x8*)&sb_hi[w * 32 + ni * 16 + r16][g * 8];
      bl[ni] = *(const bf16x8*)&sb_lo[w * 32 + ni * 16 + r16][g * 8];
    }
#pragma unroll
    for (int mi = 0; mi < 4; ++mi)
#pragma unroll
      for (int ni = 0; ni < 2; ++ni) {
        acc[mi][ni] = __builtin_amdgcn_mfma_f32_16x16x32_bf16(ah[mi], bh[ni], acc[mi][ni], 0, 0, 0);
        acc[mi][ni] = __builtin_amdgcn_mfma_f32_16x16x32_bf16(ah[mi], bl[ni], acc[mi][ni], 0, 0, 0);
        acc[mi][ni] = __builtin_amdgcn_mfma_f32_16x16x32_bf16(al[mi], bh[ni], acc[mi][ni], 0, 0, 0);
      }
  }
  // ---- epilogue ----
  if (n0 < 768) {
#pragma unroll
    for (int mi = 0; mi < 4; ++mi)
#pragma unroll
      for (int ni = 0; ni < 2; ++ni)
#pragma unroll
        for (int r = 0; r < 4; ++r) {
          int m = m0 + mi * 16 + g * 4 + r;
          int n = n0 + w * 32 + ni * 16 + r16;
          int bb = m >> 10, tt = m & 1023, h = n >> 6, d = n & 63;
          kout[(((size_t)(bb * NH + h)) * T + tt) * HS + d] = f2b(acc[mi][ni][r]);
        }
  } else {
#pragma unroll
    for (int mi = 0; mi < 4; ++mi)
#pragma unroll
      for (int ni = 0; ni < 2; ++ni)
#pragma unroll
        for (int r = 0; r < 4; ++r) {
          int m = m0 + mi * 16 + g * 4 + r;
          int n = n0 + w * 32 + ni * 16 + r16;
          linout[(size_t)m * 768 + (n - 768)] = f2b(acc[mi][ni][r]);
        }
  }
}

// ============ GEMM1: out = y @ proj_w^T (A bf16; W split in-kernel) ========
__global__ __launch_bounds__(256) void gemm1(const unsigned short* __restrict__ Y,
                                             const float* __restrict__ W0,
                                             float* __restrict__ out) {
  const int K = 768;
  __shared__ short sa_hi[64][40];
  __shared__ short sb_hi[128][40];
  __shared__ short sb_lo[128][40];
  const int tid = threadIdx.x;
  const int m0 = blockIdx.x * 64;
  const int n0 = blockIdx.y * 128;
  const int w = tid >> 6, lane = tid & 63;
  const int r16 = lane & 15, g = lane >> 4;
  const int row = tid >> 2, ac = (tid & 3) * 8;
  const int wrow = tid >> 3, wc = (tid & 7) * 4;
  const float* Wsel = W0 + (size_t)n0 * K;
  f32x4 acc[4][2];
#pragma unroll
  for (int mi = 0; mi < 4; ++mi)
#pragma unroll
    for (int ni = 0; ni < 2; ++ni) acc[mi][ni] = (f32x4){0.f, 0.f, 0.f, 0.f};

  for (int k0 = 0; k0 < K; k0 += 32) {
    __syncthreads();
#pragma unroll
    for (int i = 0; i < 4; ++i) {
      int r = wrow + 32 * i;
      float4 wv = *(const float4*)(Wsel + (size_t)r * K + k0 + wc);
      bf16x4v hi, lo;
      float vv[4] = {wv.x, wv.y, wv.z, wv.w};
#pragma unroll
      for (int e = 0; e < 4; ++e) {
        unsigned short h = f2b(vv[e]);
        hi[e] = (short)h;
        lo[e] = (short)f2b(vv[e] - b2f(h));
      }
      *(bf16x4v*)&sb_hi[r][wc] = hi;
      *(bf16x4v*)&sb_lo[r][wc] = lo;
    }
    *(bf16x8*)&sa_hi[row][ac] =
        *(const bf16x8*)(Y + (size_t)(m0 + row) * K + k0 + ac);
    __syncthreads();
    bf16x8 ah[4], bh[2], bl[2];
#pragma unroll
    for (int mi = 0; mi < 4; ++mi)
      ah[mi] = *(const bf16x8*)&sa_hi[mi * 16 + r16][g * 8];
#pragma unroll
    for (int ni = 0; ni < 2; ++ni) {
      bh[ni] = *(const bf16x8*)&sb_hi[w * 32 + ni * 16 + r16][g * 8];
      bl[ni] = *(const bf16x8*)&sb_lo[w * 32 + ni * 16 + r16][g * 8];
    }
#pragma unroll
    for (int mi = 0; mi < 4; ++mi)
#pragma unroll
      for (int ni = 0; ni < 2; ++ni) {
        acc[mi][ni] = __builtin_amdgcn_mfma_f32_16x16x32_bf16(ah[mi], bh[ni], acc[mi][ni], 0, 0, 0);
        acc[mi][ni] = __builtin_amdgcn_mfma_f32_16x16x32_bf16(ah[mi], bl[ni], acc[mi][ni], 0, 0, 0);
      }
  }
#pragma unroll
  for (int mi = 0; mi < 4; ++mi)
#pragma unroll
    for (int ni = 0; ni < 2; ++ni)
#pragma unroll
      for (int r = 0; r < 4; ++r) {
        int m = m0 + mi * 16 + g * 4 + r;
        int n = n0 + w * 32 + ni * 16 + r16;
        out[(size_t)m * 768 + n] = acc[mi][ni][r];
      }
}

// ---------------- v mixing + normalize (bf16 in -> bf16 head-major out) ----
__global__ __launch_bounds__(256) void vcompute(const unsigned short* __restrict__ lin,
                                                const float* __restrict__ coef,
                                                const float* __restrict__ vbeta,
                                                unsigned short* __restrict__ vout) {
  int w = (blockIdx.x * 256 + threadIdx.x) >> 6;
  int lane = threadIdx.x & 63;
  int t = w % T;
  int h = (w / T) % NH;
  int b = w / (T * NH);
  float c = coef[h];
  float vh = b2f(lin[((size_t)(b * T + t)) * C + h * HS + lane]);
  float vs = (t + 1 < T) ? b2f(lin[((size_t)(b * T + t + 1)) * C + h * HS + lane]) : 0.0f;
  float v = vs * (1.0f - c) + vh * c;
  float ss = v * v;
#pragma unroll
  for (int off = 1; off < 64; off <<= 1) ss += __shfl_xor(ss, off);
  float scale = rsqrtf(ss) * expf(vbeta[h] * ESCALE);
  vout[(((size_t)(b * NH + h) * T + t) * HS) + lane] = f2b(v * scale);
}

// ============ EMA as two-level chunked scan (768 independent waves) ========
__global__ __launch_bounds__(64) void ema_scan(const unsigned short* __restrict__ kb,
                                               const float* __restrict__ lkb,
                                               float* __restrict__ ends) {
  const int bx = blockIdx.x;
  const int bh = bx >> 4, ch = bx & (NCH - 1);
  const int d = threadIdx.x;
  const int h = bh % NH;
  const float lam = fabsf(lkb[h]) * ESCALE;
  const float a = expf(-lam), wf = 1.0f - a;
  const unsigned short* p = kb + (size_t)bh * T * HS + d;
  const int t0 = ch * ECH;
  float s = 0.0f;
#pragma unroll 8
  for (int t = t0; t < t0 + ECH; ++t) s = a * s + wf * b2f(p[(size_t)t * HS]);
  ends[((size_t)bh * NCH + ch) * HS + d] = s;
}

__global__ __launch_bounds__(64) void ema_apply(unsigned short* __restrict__ kb,
                                                const float* __restrict__ lkb,
                                                const float* __restrict__ kbeta,
                                                const float* __restrict__ ends) {
  const int bx = blockIdx.x;
  const int bh = bx >> 4, ch = bx & (NCH - 1);
  const int d = threadIdx.x;
  const int h = bh % NH;
  const float lam = fabsf(lkb[h]) * ESCALE;
  const float a = expf(-lam), wf = 1.0f - a;
  const float a64 = expf(-lam * (float)ECH);
  const float kbs = expf(fminf(kbeta[h] * ESCALE, KBUP));
  unsigned short* p = kb + (size_t)bh * T * HS + d;
  float carry = 0.0f;
  for (int c = 0; c < ch; ++c)
    carry = a64 * carry + ends[((size_t)bh * NCH + c) * HS + d];
  float s = carry;
  const int t0 = ch * ECH;
  for (int tb = 0; tb < ECH; tb += 8) {
    float sr[8], q[8];
#pragma unroll
    for (int u = 0; u < 8; ++u) {
      s = a * s + wf * b2f(p[(size_t)(t0 + tb + u) * HS]);
      sr[u] = s;
    }
#pragma unroll
    for (int u = 0; u < 8; ++u) q[u] = sr[u] * sr[u];
#pragma unroll
    for (int off = 1; off < 64; off <<= 1)
#pragma unroll
      for (int u = 0; u < 8; ++u) q[u] += __shfl_xor(q[u], off);
#pragma unroll
    for (int u = 0; u < 8; ++u)
      p[(size_t)(t0 + tb + u) * HS] = f2b(sr[u] * rsqrtf(q[u]) * kbs);
  }
}

// ---------------- MFMA flash attention (bf16 K/V, swapped-QK^T) ------------
__global__ __launch_bounds__(256) void attn_mfma(const unsigned short* __restrict__ Km,
                                                 const unsigned short* __restrict__ Vm,
                                                 unsigned short* __restrict__ Y) {
  const int bid = blockIdx.x;
  const int qt = 15 - (bid / (B * NH));  // heavy q-tiles first
  const int bh = bid % (B * NH);
  const int b = bh / NH, h = bh % NH;
  const int qi0 = qt * 64;
  const short* Kb = (const short*)(Km + (size_t)bh * T * HS);
  const short* Vb = (const short*)(Vm + (size_t)bh * T * HS);
  __shared__ short kt[64 * 72];
  __shared__ short vt[64 * 72];
  __shared__ short pl[4 * 16 * 72];
  const int tid = threadIdx.x;
  const int w = tid >> 6, lane = tid & 63;
  const int qr = lane & 15, qg = lane >> 4;

  bf16x8 qf0 = *(const bf16x8*)(Kb + (size_t)(qi0 + w * 16 + qr) * HS + qg * 8);
  bf16x8 qf1 = *(const bf16x8*)(Kb + (size_t)(qi0 + w * 16 + qr) * HS + qg * 8 + 32);

  f32x4 o[4];
#pragma unroll
  for (int db = 0; db < 4; ++db) o[db] = (f32x4){0.f, 0.f, 0.f, 0.f};
  float m_st = -INFINITY, l_st = 0.0f;

  const int njt = qt + 1;
  for (int jt = 0; jt < njt; ++jt) {
    const int j0 = jt * 64;
    __syncthreads();
#pragma unroll
    for (int it = 0; it < 2; ++it) {
      int idx = tid + it * 256;
      int row = idx >> 3, ch = idx & 7;
      *(bf16x8*)&kt[row * 72 + ch * 8] =
          *(const bf16x8*)(Kb + (size_t)(j0 + row) * HS + ch * 8);
      int vj = idx & 63, vd0 = (idx >> 6) * 8;
      bf16x8 vv = *(const bf16x8*)(Vb + (size_t)(j0 + vj) * HS + vd0);
#pragma unroll
      for (int e = 0; e < 8; ++e) vt[(vd0 + e) * 72 + vj] = vv[e];
    }
    __syncthreads();
    f32x4 st[4];
#pragma unroll
    for (int jb = 0; jb < 4; ++jb) st[jb] = (f32x4){0.f, 0.f, 0.f, 0.f};
#pragma unroll
    for (int jb = 0; jb < 4; ++jb) {
      bf16x8 kf0 = *(const bf16x8*)&kt[(qr + 16 * jb) * 72 + qg * 8];
      bf16x8 kf1 = *(const bf16x8*)&kt[(qr + 16 * jb) * 72 + qg * 8 + 32];
      st[jb] = __builtin_amdgcn_mfma_f32_16x16x32_bf16(kf0, qf0, st[jb], 0, 0, 0);
      st[jb] = __builtin_amdgcn_mfma_f32_16x16x32_bf16(kf1, qf1, st[jb], 0, 0, 0);
    }
    if (jt == njt - 1) {
      const int ii = qi0 + w * 16 + qr;
#pragma unroll
      for (int jb = 0; jb < 4; ++jb)
#pragma unroll
        for (int r = 0; r < 4; ++r) {
          int jj = j0 + 16 * jb + qg * 4 + r;
          if (jj >= ii) st[jb][r] = -INFINITY;
        }
    }
    float rm = -INFINITY;
#pragma unroll
    for (int jb = 0; jb < 4; ++jb)
#pragma unroll
      for (int r = 0; r < 4; ++r) rm = fmaxf(rm, st[jb][r]);
    rm = fmaxf(rm, __shfl_xor(rm, 16));
    rm = fmaxf(rm, __shfl_xor(rm, 32));
    float mnew = fmaxf(m_st, rm);
    float scale = (mnew == -INFINITY) ? 1.0f : __expf(m_st - mnew);
    float p[4][4];
    float rs = 0.0f;
#pragma unroll
    for (int jb = 0; jb < 4; ++jb)
#pragma unroll
      for (int r = 0; r < 4; ++r) {
        float pv = (st[jb][r] == -INFINITY) ? 0.0f : __expf(st[jb][r] - mnew);
        p[jb][r] = pv;
        rs += pv;
      }
    rs += __shfl_xor(rs, 16);
    rs += __shfl_xor(rs, 32);
    l_st = l_st * scale + rs;
    m_st = mnew;
#pragma unroll
    for (int db = 0; db < 4; ++db) o[db] *= scale;
#pragma unroll
    for (int jb = 0; jb < 4; ++jb) {
      bf16x4v pw;
#pragma unroll
      for (int r = 0; r < 4; ++r) pw[r] = (short)f2b(p[jb][r]);
      *(bf16x4v*)&pl[w * 1152 + qr * 72 + jb * 16 + qg * 4] = pw;
    }
#pragma unroll
    for (int ks = 0; ks < 2; ++ks) {
      bf16x8 pf = *(const bf16x8*)&pl[w * 1152 + qr * 72 + ks * 32 + qg * 8];
#pragma unroll
      for (int db = 0; db < 4; ++db) {
        bf16x8 vf = *(const bf16x8*)&vt[(qr + 16 * db) * 72 + qg * 8 + ks * 32];
        o[db] = __builtin_amdgcn_mfma_f32_16x16x32_bf16(vf, pf, o[db], 0, 0, 0);
      }
    }
  }
  float inv = (l_st > 0.0f) ? 1.0f / l_st : 0.0f;
#pragma unroll
  for (int db = 0; db < 4; ++db) {
    bf16x4v yv;
#pragma unroll
    for (int r = 0; r < 4; ++r) yv[r] = (short)f2b(o[db][r] * inv);
    *(bf16x4v*)(Y + (size_t)(b * T + qi0 + w * 16 + qr) * C + h * HS + db * 16 + qg * 4) = yv;
  }
}

extern "C" void kernel_launch(void* const* d_in, const int* in_sizes, int n_in,
                              void* d_out, int out_size, void* d_ws, size_t ws_size,
                              hipStream_t stream) {
  const float* x = (const float*)d_in[0];
  const float* conv_w = (const float*)d_in[1];
  const float* lin_w = (const float*)d_in[2];
  const float* coef = (const float*)d_in[3];
  const float* lkb = (const float*)d_in[4];
  const float* kbeta = (const float*)d_in[5];
  const float* vbeta = (const float*)d_in[6];
  const float* proj_w = (const float*)d_in[7];

  // Proven budget: ws 12.58 MB + d_out 12.58 MB. Timeline (no live overlaps):
  //   ws:    [k bf16 NE | Wc/Wl hi+lo splits 4*WE | ends 196KB]
  //          -> after gemm0+ema: [k | y bf16 NE (over dead splits+ends)]
  //   d_out: [lin bf16 NE | v bf16 NE] -> final fp32 out overwrites all.
  const size_t NE = (size_t)B * T * C;
  unsigned short* wsu = (unsigned short*)d_ws;
  unsigned short* kbuf = wsu;                    // [0 : NE)
  unsigned short* wsplit = wsu + NE;             // [NE : NE+4*WE)
  float* ends = (float*)(wsu + NE + 4 * WE);     // 196 KB
  unsigned short* ybuf = wsu + NE;               // y over dead wsplit+ends
  unsigned short* linbuf = (unsigned short*)d_out;  // [0 : NE)
  unsigned short* vbuf = linbuf + NE;               // [NE : 2NE)

  split_w<<<2 * WE / 1024, 256, 0, stream>>>(conv_w, lin_w, wsplit);
  gemm0<<<dim3(64, 12), 256, 0, stream>>>(x, wsplit, kbuf, linbuf);
  vcompute<<<(B * NH * T) / 4, 256, 0, stream>>>(linbuf, coef, vbeta, vbuf);
  ema_scan<<<B * NH * NCH, 64, 0, stream>>>(kbuf, lkb, ends);
  ema_apply<<<B * NH * NCH, 64, 0, stream>>>(kbuf, lkb, kbeta, ends);
  attn_mfma<<<T / 64 * B * NH, 256, 0, stream>>>(kbuf, vbuf, ybuf);
  gemm1<<<dim3(64, 6), 256, 0, stream>>>(ybuf, proj_w, (float*)d_out);
}